// Round 10
// baseline (169.574 us; speedup 1.0000x reference)
//
#include <hip/hip_runtime.h>
#include <hip/hip_bf16.h>
#include <cstdio>

typedef __hip_bfloat16 bf16;
typedef __bf16 bf16x8 __attribute__((ext_vector_type(8)));
typedef float f32x16 __attribute__((ext_vector_type(16)));

#define B_DIM 4
#define T_DIM 4096
#define D_DIM 1024
#define NC 64   // chunks along T
#define LC 64   // chunk length; NC*LC == T_DIM

#define M_DIM (B_DIM * T_DIM)  // 16384
#define BM 256
#define BN 256
#define BK 32
#define NT (D_DIM / BK)        // 32 K-tiles
#define GM (M_DIM / BM)        // 64
#define GN (D_DIM / BN)        // 4

// ---------------------------------------------------------------- weight cast
__global__ __launch_bounds__(256) void cast_w_kernel(
    const float* __restrict__ gw, const float* __restrict__ ow,
    bf16* __restrict__ gw16, bf16* __restrict__ ow16, int n) {
  int i = blockIdx.x * 256 + threadIdx.x;
  if (i < n) {
    gw16[i] = __float2bfloat16(gw[i]);
    ow16[i] = __float2bfloat16(ow[i]);
  }
}

// ---------------------------------------------------------------- SSM pass 1
__global__ __launch_bounds__(256) void ssm_pass1(
    const float* __restrict__ x, const float* __restrict__ A,
    const float* __restrict__ Bp, float* __restrict__ hfin) {
  const int tid  = threadIdx.x;
  const int dblk = blockIdx.x & 3;           // D/256 = 4
  const int c    = (blockIdx.x >> 2) & (NC - 1);
  const int b    = blockIdx.x >> 8;          // / (4*NC)
  const int d    = dblk * 256 + tid;
  const float a = A[d], bp = Bp[d];
  const float* p = x + ((size_t)(b * T_DIM + c * LC) * D_DIM + d);
  float h = 0.f;
#pragma unroll 4
  for (int i = 0; i < LC; ++i)
    h = fmaf(a, h, bp * p[(size_t)i * D_DIM]);
  hfin[(b * NC + c) * D_DIM + d] = h;
}

// ---------------------------------------------------------------- SSM pass 2
__global__ __launch_bounds__(256) void ssm_pass2(
    const float* __restrict__ A, const float* __restrict__ hfin,
    float* __restrict__ hin) {
  const int idx = blockIdx.x * 256 + threadIdx.x;  // B*D = 4096
  const int d = idx & (D_DIM - 1);
  const int b = idx >> 10;
  float aL = A[d];
#pragma unroll
  for (int s = 0; s < 6; ++s) aL *= aL;  // A^64 (LC = 2^6)
  float h = 0.f;
  for (int c = 0; c < NC; ++c) {
    const int o = (b * NC + c) * D_DIM + d;
    hin[o] = h;
    h = fmaf(aL, h, hfin[o]);
  }
}

// ---------------------------------------------------------------- SSM pass 3
__global__ __launch_bounds__(256) void ssm_pass3(
    const float* __restrict__ x, const float* __restrict__ A,
    const float* __restrict__ Bp, const float* __restrict__ Cp,
    const float* __restrict__ hin, bf16* __restrict__ ssm16,
    bf16* __restrict__ x16) {
  const int tid  = threadIdx.x;
  const int dblk = blockIdx.x & 3;
  const int c    = (blockIdx.x >> 2) & (NC - 1);
  const int b    = blockIdx.x >> 8;
  const int d    = dblk * 256 + tid;
  const float a = A[d], bp = Bp[d], cp = Cp[d];
  float h = hin[(b * NC + c) * D_DIM + d];
  const size_t base = (size_t)(b * T_DIM + c * LC) * D_DIM + d;
#pragma unroll 4
  for (int i = 0; i < LC; ++i) {
    const size_t o = base + (size_t)i * D_DIM;
    const float xv = x[o];
    h = fmaf(a, h, bp * xv);
    ssm16[o] = __float2bfloat16(cp * h);
    x16[o]  = __float2bfloat16(xv);
  }
}

// ---------------------------------------------------------------- GEMM 256x256
// C[m][e] = sum_k X[m][k] * W[e][k]  (+bias, +epilogue)
// R10 = R9 ring-4 schedule with the inner tile switched to
// mfma_f32_32x32x16_bf16 (16 FLOP per LDS byte vs 8): per wave per K-tile,
// 12 ds_read_b128 now feed 16 32x32 MFMAs (2x FLOP of the 16x16 path) —
// LDS pipe (measured co-critical with MFMA pipe at R9) drops ~2x.
// LDS layout = chunked-K-major: 16B chunk index L = k8*256 + row
// (k8 = k-octet 0..3 within BK=32). Staging keeps the LINEAR LDS dest
// (global_load_lds requirement) and folds the permutation into the
// per-lane GLOBAL address (m173). Frag reads: lanes 0..31 hit 32
// consecutive 16B chunks -> conflict-free by construction, no XOR.
// A/B frag: lane l holds row/col (l&31), k = kk*16 + (l>>5)*8 + [0,8).
// C/D: col = lane&31, row = (reg&3)+8*(reg>>2)+4*(lane>>5)  [m74/m101].
// Ring-4, prefetch dist 3, counted vmcnt 8/4/0 (T4), mid-tile single
// barrier with kk=0/kk=1 MFMA halves, T5 setprio, XCD-chunked swizzle.
template <bool GATE>
__global__ __launch_bounds__(512) void gemm256(
    const bf16* __restrict__ Xm, const bf16* __restrict__ Wm,
    const float* __restrict__ bias, const bf16* __restrict__ ssm,
    bf16* __restrict__ Ybf, float* __restrict__ Yf) {
  // buf (shorts): [0,8192) = A tile (1024 chunks), [8192,16384) = B tile
  __shared__ __align__(16) short LDS[4][16384];  // 4 x 32 KiB = 128 KiB

  const int tid  = threadIdx.x;
  const int lane = tid & 63;
  const int wave = tid >> 6;
  const int wm = wave >> 2;           // 0..1  (M half)
  const int wn = wave & 3;            // 0..3  (N quarter)
  const int fr = lane & 31;           // frag row/col
  const int k8 = lane >> 5;           // k-octet select within frag

  // XCD-chunked swizzle (256 blocks, 8 XCDs): 4 N-blocks per M-row share L2.
  const int bid = blockIdx.x;
  const int swz = (bid & 7) * (GM * GN / 8) + (bid >> 3);
  const int m0 = (swz >> 2) * BM;
  const int n0 = (swz & 3) * BN;

  // staging: LDS chunk L = it*512 + tid (linear dest); global source for
  // chunk L: row = L&255, octet = L>>8  ->  g = (base+row)*D + kt*32 + oct*8
  size_t offA[2], offB[2];
#pragma unroll
  for (int it = 0; it < 2; ++it) {
    const int L   = it * 512 + tid;
    const int row = L & 255;
    const int oct = L >> 8;
    offA[it] = (size_t)(m0 + row) * D_DIM + oct * 8;
    offB[it] = (size_t)(n0 + row) * D_DIM + oct * 8;
  }

  auto gll = [](const bf16* g, short* l) {
    __builtin_amdgcn_global_load_lds(
        (const __attribute__((address_space(1))) void*)g,
        (__attribute__((address_space(3))) void*)l, 16, 0, 0);
  };
  auto STAGE = [&](int buf, int kt) {
    const size_t ko = (size_t)kt * BK;
    short* b0 = &LDS[buf][0] + wave * 512;  // wave-uniform linear dest
    gll(Xm + offA[0] + ko, b0);
    gll(Xm + offA[1] + ko, b0 + 4096);
    gll(Wm + offB[0] + ko, b0 + 8192);
    gll(Wm + offB[1] + ko, b0 + 12288);
  };

  f32x16 acc[4][2] = {};

  // frag base offsets (shorts): chunk (k8*256 + row) * 8
  const int aBase = (k8 * 256 + wm * 128 + fr) * 8;         // + i*32*8
  const int bBase = 8192 + (k8 * 256 + wn * 64 + fr) * 8;   // + j*32*8

  // prologue: prime tiles 0,1,2 (12 loads/thread in flight)
  STAGE(0, 0);
  STAGE(1, 1);
  STAGE(2, 2);
  asm volatile("s_waitcnt vmcnt(8)" ::: "memory");
  __builtin_amdgcn_s_barrier();  // tile 0 staged for all waves

#define KTILE_BODY(T_, VMSTR, DO_STAGE, DO_BAR)                             \
  {                                                                         \
    const short* bb = &LDS[(T_) & 3][0];                                    \
    bf16x8 a0[4], b0[2], a1[4], b1[2];                                      \
    _Pragma("unroll")                                                       \
    for (int i = 0; i < 4; ++i)                                             \
      a0[i] = *(const bf16x8*)(bb + aBase + i * 256);                       \
    _Pragma("unroll")                                                       \
    for (int j = 0; j < 2; ++j)                                             \
      b0[j] = *(const bf16x8*)(bb + bBase + j * 256);                       \
    _Pragma("unroll")                                                       \
    for (int i = 0; i < 4; ++i)                                             \
      a1[i] = *(const bf16x8*)(bb + aBase + 4096 + i * 256);                \
    _Pragma("unroll")                                                       \
    for (int j = 0; j < 2; ++j)                                             \
      b1[j] = *(const bf16x8*)(bb + bBase + 4096 + j * 256);                \
    if (DO_STAGE) STAGE(((T_) + 3) & 3, (T_) + 3);                          \
    __builtin_amdgcn_s_setprio(1);                                          \
    _Pragma("unroll")                                                       \
    for (int i = 0; i < 4; ++i)                                             \
      _Pragma("unroll")                                                     \
      for (int j = 0; j < 2; ++j)                                           \
        acc[i][j] = __builtin_amdgcn_mfma_f32_32x32x16_bf16(                \
            a0[i], b0[j], acc[i][j], 0, 0, 0);                              \
    __builtin_amdgcn_s_setprio(0);                                          \
    if (DO_BAR) {                                                           \
      asm volatile("s_waitcnt " VMSTR ::: "memory");                        \
      __builtin_amdgcn_s_barrier();                                         \
    }                                                                       \
    __builtin_amdgcn_s_setprio(1);                                          \
    _Pragma("unroll")                                                       \
    for (int i = 0; i < 4; ++i)                                             \
      _Pragma("unroll")                                                     \
      for (int j = 0; j < 2; ++j)                                           \
        acc[i][j] = __builtin_amdgcn_mfma_f32_32x32x16_bf16(                \
            a1[i], b1[j], acc[i][j], 0, 0, 0);                              \
    __builtin_amdgcn_s_setprio(0);                                          \
  }

  for (int t = 0; t < NT - 3; ++t)        // t = 0..28: stage t+3 = 3..31
    KTILE_BODY(t, "vmcnt(8)", true, true);
  KTILE_BODY(NT - 3, "vmcnt(4)", false, true);  // ensure tile NT-2 landed
  KTILE_BODY(NT - 2, "vmcnt(0)", false, true);  // ensure tile NT-1 landed
  KTILE_BODY(NT - 1, "vmcnt(0)", false, false); // last tile: no barrier
#undef KTILE_BODY

  // ---- epilogue: col = lane&31, row = (r&3)+8*(r>>2)+4*(lane>>5) [m74/m101]
#pragma unroll
  for (int i = 0; i < 4; ++i) {
#pragma unroll
    for (int j = 0; j < 2; ++j) {
      const int col = n0 + wn * 64 + j * 32 + fr;
      const float bv = bias[col];
#pragma unroll
      for (int r = 0; r < 16; ++r) {
        const int row = m0 + wm * 128 + i * 32 + (r & 3) + 8 * (r >> 2) + 4 * k8;
        const size_t o = (size_t)row * D_DIM + col;
        const float val = acc[i][j][r] + bv;
        if (GATE) {
          const float g = 1.f / (1.f + expf(-val));
          Ybf[o] = __float2bfloat16(g * __bfloat162float(ssm[o]));
        } else {
          Yf[o] = val;
        }
      }
    }
  }
}

// ---------------------------------------------------------------- launch
extern "C" void kernel_launch(void* const* d_in, const int* in_sizes, int n_in,
                              void* d_out, int out_size, void* d_ws, size_t ws_size,
                              hipStream_t stream) {
  const float* x  = (const float*)d_in[0];
  const float* A  = (const float*)d_in[1];
  const float* Bp = (const float*)d_in[2];
  const float* Cp = (const float*)d_in[3];
  const float* gw = (const float*)d_in[4];
  const float* gb = (const float*)d_in[5];
  const float* ow = (const float*)d_in[6];
  const float* ob = (const float*)d_in[7];
  float* out = (float*)d_out;

  // workspace layout (bytes)
  const size_t NEED = 73400320;
  if (ws_size < NEED) {
    fprintf(stderr, "kernel_launch: ws_size %zu < needed %zu\n", ws_size, NEED);
    return;
  }
  char* ws = (char*)d_ws;
  bf16*  x16   = (bf16*)(ws);                   // 33,554,432 B : x cast to bf16
  bf16*  ssm16 = (bf16*)(ws + 33554432);        // 33,554,432 B : ssm, then y in-place
  bf16*  gw16  = (bf16*)(ws + 67108864);        //  2,097,152 B
  bf16*  ow16  = (bf16*)(ws + 69206016);        //  2,097,152 B
  float* hfin  = (float*)(ws + 71303168);       //  1,048,576 B
  float* hin   = (float*)(ws + 72351744);       //  1,048,576 B

  cast_w_kernel<<<(D_DIM * D_DIM) / 256, 256, 0, stream>>>(gw, ow, gw16, ow16, D_DIM * D_DIM);
  ssm_pass1<<<B_DIM * NC * (D_DIM / 256), 256, 0, stream>>>(x, A, Bp, hfin);
  ssm_pass2<<<(B_DIM * D_DIM) / 256, 256, 0, stream>>>(A, hfin, hin);
  ssm_pass3<<<B_DIM * NC * (D_DIM / 256), 256, 0, stream>>>(x, A, Bp, Cp, hin, ssm16, x16);

  // gate GEMM: y = sigmoid(x@gw^T + gb) * ssm   (written in-place over ssm16)
  gemm256<true><<<GM * GN, 512, 0, stream>>>(x16, gw16, gb, ssm16, ssm16, nullptr);
  // out GEMM: out = y@ow^T + ob  (fp32)
  gemm256<false><<<GM * GN, 512, 0, stream>>>(ssm16, ow16, ob, nullptr, nullptr, out);
}

// Round 12
// 134.528 us; speedup vs baseline: 1.2605x; 1.2605x over previous
//
#include <hip/hip_runtime.h>
#include <hip/hip_bf16.h>
#include <cstdio>

typedef __hip_bfloat16 bf16;
typedef __bf16 bf16x8 __attribute__((ext_vector_type(8)));
typedef float f32x4 __attribute__((ext_vector_type(4)));

#define B_DIM 4
#define T_DIM 4096
#define D_DIM 1024
#define NC 64   // chunks along T
#define LC 64   // chunk length; NC*LC == T_DIM

#define M_DIM (B_DIM * T_DIM)  // 16384
#define BM 256
#define BN 128
#define BK 32
#define NT (D_DIM / BK)        // 32 K-tiles
#define GM (M_DIM / BM)        // 64
#define GN (D_DIM / BN)        // 8

// ---------------------------------------------------------------- weight cast
__global__ __launch_bounds__(256) void cast_w_kernel(
    const float* __restrict__ gw, const float* __restrict__ ow,
    bf16* __restrict__ gw16, bf16* __restrict__ ow16, int n) {
  int i = blockIdx.x * 256 + threadIdx.x;
  if (i < n) {
    gw16[i] = __float2bfloat16(gw[i]);
    ow16[i] = __float2bfloat16(ow[i]);
  }
}

// ---------------------------------------------------------------- SSM pass 1
__global__ __launch_bounds__(256) void ssm_pass1(
    const float* __restrict__ x, const float* __restrict__ A,
    const float* __restrict__ Bp, float* __restrict__ hfin) {
  const int tid  = threadIdx.x;
  const int dblk = blockIdx.x & 3;           // D/256 = 4
  const int c    = (blockIdx.x >> 2) & (NC - 1);
  const int b    = blockIdx.x >> 8;          // / (4*NC)
  const int d    = dblk * 256 + tid;
  const float a = A[d], bp = Bp[d];
  const float* p = x + ((size_t)(b * T_DIM + c * LC) * D_DIM + d);
  float h = 0.f;
#pragma unroll 4
  for (int i = 0; i < LC; ++i)
    h = fmaf(a, h, bp * p[(size_t)i * D_DIM]);
  hfin[(b * NC + c) * D_DIM + d] = h;
}

// ---------------------------------------------------------------- SSM pass 2
__global__ __launch_bounds__(256) void ssm_pass2(
    const float* __restrict__ A, const float* __restrict__ hfin,
    float* __restrict__ hin) {
  const int idx = blockIdx.x * 256 + threadIdx.x;  // B*D = 4096
  const int d = idx & (D_DIM - 1);
  const int b = idx >> 10;
  float aL = A[d];
#pragma unroll
  for (int s = 0; s < 6; ++s) aL *= aL;  // A^64 (LC = 2^6)
  float h = 0.f;
  for (int c = 0; c < NC; ++c) {
    const int o = (b * NC + c) * D_DIM + d;
    hin[o] = h;
    h = fmaf(aL, h, hfin[o]);
  }
}

// ---------------------------------------------------------------- SSM pass 3
__global__ __launch_bounds__(256) void ssm_pass3(
    const float* __restrict__ x, const float* __restrict__ A,
    const float* __restrict__ Bp, const float* __restrict__ Cp,
    const float* __restrict__ hin, bf16* __restrict__ ssm16,
    bf16* __restrict__ x16) {
  const int tid  = threadIdx.x;
  const int dblk = blockIdx.x & 3;
  const int c    = (blockIdx.x >> 2) & (NC - 1);
  const int b    = blockIdx.x >> 8;
  const int d    = dblk * 256 + tid;
  const float a = A[d], bp = Bp[d], cp = Cp[d];
  float h = hin[(b * NC + c) * D_DIM + d];
  const size_t base = (size_t)(b * T_DIM + c * LC) * D_DIM + d;
#pragma unroll 4
  for (int i = 0; i < LC; ++i) {
    const size_t o = base + (size_t)i * D_DIM;
    const float xv = x[o];
    h = fmaf(a, h, bp * xv);
    ssm16[o] = __float2bfloat16(cp * h);
    x16[o]  = __float2bfloat16(xv);
  }
}

// ---------------------------------------------------------------- GEMM 256x128
// C[m][e] = sum_k X[m][k] * W[e][k]  (+bias, +epilogue)
// R11: R9 choreography, re-tiled for 2 blocks/CU (fix the 1-block/CU
// barrier convoy; R8's variant failed because it used 4-wave blocks).
//  - tile 256x128, grid 512 (2 blocks/CU), 8 waves (4M x 2N), wave-tile
//    64x64: a[4] x b[4] -> 16 MFMA 16x16x32, acc[4][4] f32x4 = 64 regs.
//  - __launch_bounds__(512,4): cap total regs at 128 -> 4 waves/SIMD
//    (16 waves/CU). Two independent barrier domains: while one block
//    drains vmcnt/barrier, the other block's MFMAs issue (m114).
//  - ring-3 LDS 72 KiB (A 16K + B 8K per buf), prefetch distance 2.
//  - vmcnt ledger (3 loads/thread/STAGE): prologue stage{0,1}, vmcnt(3)
//    [tile0 done]; tile t: STAGE(t+2) -> <=6 outstanding; mid vmcnt(3)
//    [only t+2's remain -> t+1 done]; tail vmcnt(0); last tile no barrier.
//  - lifetime: STAGE(t+2) overwrites buf[(t-1)%3]; all waves' reads of
//    buf[t-1] complete before their tile-(t-1) MFMAs (lgkmcnt), which
//    precede the t-1 mid-barrier that all waves cross before any wave
//    issues STAGE(t+2) at tile t. Safe.
//  - T2 XOR swizzle both-sides (verified 0 conflicts), T5 setprio,
//    XCD-chunked bijective swizzle (512 % 8 == 0).
template <bool GATE>
__global__ __launch_bounds__(512, 4) void gemm256(
    const bf16* __restrict__ Xm, const bf16* __restrict__ Wm,
    const float* __restrict__ bias, const bf16* __restrict__ ssm,
    bf16* __restrict__ Ybf, float* __restrict__ Yf) {
  // buf (shorts): [0,8192) = A tile 256x32, [8192,12288) = B tile 128x32
  __shared__ __align__(16) short LDS[3][12288];  // 3 x 24 KiB = 72 KiB

  const int tid  = threadIdx.x;
  const int lane = tid & 63;
  const int wave = tid >> 6;
  const int wr = wave >> 1;           // 0..3  (M quarter)
  const int wc = wave & 1;            // 0..1  (N half)
  const int l15 = lane & 15;
  // swizzled ds_read slot: true chunk (lane>>4), row parity term (l15>>1)&3
  const int sA = ((lane >> 4) ^ ((l15 >> 1) & 3)) << 3;  // shorts

  // XCD-chunked swizzle (512 blocks, 8 XCDs, 64/XCD): the 8 N-blocks of
  // each M-row are consecutive within an XCD chunk (A-panel L2 reuse).
  const int bid = blockIdx.x;
  const int swz = (bid & 7) * (GM * GN / 8) + (bid >> 3);
  const int m0 = (swz >> 3) * BM;     // swz / GN
  const int n0 = (swz & 7) * BN;      // swz % GN

  // staging: linear LDS chunk cid -> row=cid>>2, slot=cid&3; global col-chunk
  // c = slot ^ ((row>>1)&3)  (involution matches sA on the read side).
  // Thread handles A chunks {tid, tid+512} and B chunk {tid}.
  const int row0 = tid >> 2;          // 0..127
  const int c0   = (tid & 3) ^ ((row0 >> 1) & 3);
  // note: row(tid+512) = row0+128; ((row0+128)>>1)&3 == (row0>>1)&3, so the
  // same c0 applies to the second A chunk.
  const size_t offA0 = (size_t)(m0 + row0) * D_DIM + c0 * 8;
  const size_t offA1 = offA0 + (size_t)128 * D_DIM;
  const size_t offB0 = (size_t)(n0 + row0) * D_DIM + c0 * 8;

  auto gll = [](const bf16* g, short* l) {
    __builtin_amdgcn_global_load_lds(
        (const __attribute__((address_space(1))) void*)g,
        (__attribute__((address_space(3))) void*)l, 16, 0, 0);
  };
  auto STAGE = [&](int buf, int kt) {
    const size_t ko = (size_t)kt * BK;
    short* b0 = &LDS[buf][0] + wave * 512;  // wave-uniform linear dest
    gll(Xm + offA0 + ko, b0);
    gll(Xm + offA1 + ko, b0 + 4096);
    gll(Wm + offB0 + ko, b0 + 8192);
  };

  f32x4 acc[4][4] = {};

  // prologue: prime tiles 0,1 (6 loads/thread in flight)
  STAGE(0, 0);
  STAGE(1, 1);
  asm volatile("s_waitcnt vmcnt(3)" ::: "memory");
  __builtin_amdgcn_s_barrier();  // tile 0 staged for all waves

#define KTILE_BODY(RB_, SB_, KT2_, VMSTR, DO_STAGE, DO_BAR)                 \
  {                                                                         \
    const short* bb = &LDS[RB_][0];                                         \
    bf16x8 a[4], b[4];                                                      \
    _Pragma("unroll")                                                       \
    for (int i = 0; i < 4; ++i)                                             \
      a[i] = *(const bf16x8*)(bb + (wr * 64 + i * 16 + l15) * BK + sA);     \
    _Pragma("unroll")                                                       \
    for (int j = 0; j < 4; ++j)                                             \
      b[j] = *(const bf16x8*)(bb + 8192 + (wc * 64 + j * 16 + l15) * BK + sA); \
    if (DO_STAGE) STAGE(SB_, KT2_);                                         \
    __builtin_amdgcn_s_setprio(1);                                          \
    _Pragma("unroll")                                                       \
    for (int i = 0; i < 4; ++i)                                             \
      _Pragma("unroll")                                                     \
      for (int j = 0; j < 2; ++j)                                           \
        acc[i][j] =                                                         \
            __builtin_amdgcn_mfma_f32_16x16x32_bf16(a[i], b[j], acc[i][j], 0, 0, 0); \
    __builtin_amdgcn_s_setprio(0);                                          \
    if (DO_BAR) {                                                           \
      asm volatile("s_waitcnt " VMSTR ::: "memory");                        \
      __builtin_amdgcn_s_barrier();                                         \
    }                                                                       \
    __builtin_amdgcn_s_setprio(1);                                          \
    _Pragma("unroll")                                                       \
    for (int i = 0; i < 4; ++i)                                             \
      _Pragma("unroll")                                                     \
      for (int j = 2; j < 4; ++j)                                           \
        acc[i][j] =                                                         \
            __builtin_amdgcn_mfma_f32_16x16x32_bf16(a[i], b[j], acc[i][j], 0, 0, 0); \
    __builtin_amdgcn_s_setprio(0);                                          \
  }

  {
    int rb = 0;
    for (int t = 0; t < NT - 2; ++t) {  // t = 0..29: stage t+2 = 2..31
      int sb = rb + 2; if (sb >= 3) sb -= 3;
      KTILE_BODY(rb, sb, t + 2, "vmcnt(3)", true, true);
      ++rb; if (rb == 3) rb = 0;
    }
  }
  KTILE_BODY((NT - 2) % 3, 0, 0, "vmcnt(0)", false, true);   // tile 31 landed
  KTILE_BODY((NT - 1) % 3, 0, 0, "vmcnt(0)", false, false);  // last, no barrier
#undef KTILE_BODY

  // ---- epilogue: C/D layout col = lane&15, row = (lane>>4)*4 + v  [m89/m91]
#pragma unroll
  for (int i = 0; i < 4; ++i) {
#pragma unroll
    for (int j = 0; j < 4; ++j) {
      const int col = n0 + wc * 64 + j * 16 + l15;
      const float bv = bias[col];
#pragma unroll
      for (int v = 0; v < 4; ++v) {
        const int row = m0 + wr * 64 + i * 16 + (lane >> 4) * 4 + v;
        const size_t o = (size_t)row * D_DIM + col;
        const float val = acc[i][j][v] + bv;
        if (GATE) {
          const float g = 1.f / (1.f + expf(-val));
          Ybf[o] = __float2bfloat16(g * __bfloat162float(ssm[o]));
        } else {
          Yf[o] = val;
        }
      }
    }
  }
}

// ---------------------------------------------------------------- launch
extern "C" void kernel_launch(void* const* d_in, const int* in_sizes, int n_in,
                              void* d_out, int out_size, void* d_ws, size_t ws_size,
                              hipStream_t stream) {
  const float* x  = (const float*)d_in[0];
  const float* A  = (const float*)d_in[1];
  const float* Bp = (const float*)d_in[2];
  const float* Cp = (const float*)d_in[3];
  const float* gw = (const float*)d_in[4];
  const float* gb = (const float*)d_in[5];
  const float* ow = (const float*)d_in[6];
  const float* ob = (const float*)d_in[7];
  float* out = (float*)d_out;

  // workspace layout (bytes)
  const size_t NEED = 73400320;
  if (ws_size < NEED) {
    fprintf(stderr, "kernel_launch: ws_size %zu < needed %zu\n", ws_size, NEED);
    return;
  }
  char* ws = (char*)d_ws;
  bf16*  x16   = (bf16*)(ws);                   // 33,554,432 B : x cast to bf16
  bf16*  ssm16 = (bf16*)(ws + 33554432);        // 33,554,432 B : ssm, then y in-place
  bf16*  gw16  = (bf16*)(ws + 67108864);        //  2,097,152 B
  bf16*  ow16  = (bf16*)(ws + 69206016);        //  2,097,152 B
  float* hfin  = (float*)(ws + 71303168);       //  1,048,576 B
  float* hin   = (float*)(ws + 72351744);       //  1,048,576 B

  cast_w_kernel<<<(D_DIM * D_DIM) / 256, 256, 0, stream>>>(gw, ow, gw16, ow16, D_DIM * D_DIM);
  ssm_pass1<<<B_DIM * NC * (D_DIM / 256), 256, 0, stream>>>(x, A, Bp, hfin);
  ssm_pass2<<<(B_DIM * D_DIM) / 256, 256, 0, stream>>>(A, hfin, hin);
  ssm_pass3<<<B_DIM * NC * (D_DIM / 256), 256, 0, stream>>>(x, A, Bp, Cp, hin, ssm16, x16);

  // gate GEMM: y = sigmoid(x@gw^T + gb) * ssm   (written in-place over ssm16)
  gemm256<true><<<GM * GN, 512, 0, stream>>>(x16, gw16, gb, ssm16, ssm16, nullptr);
  // out GEMM: out = y@ow^T + ob  (fp32)
  gemm256<false><<<GM * GN, 512, 0, stream>>>(ssm16, ow16, ob, nullptr, nullptr, out);
}

// Round 13
// 133.331 us; speedup vs baseline: 1.2718x; 1.0090x over previous
//
#include <hip/hip_runtime.h>
#include <hip/hip_bf16.h>
#include <cstdio>

typedef __hip_bfloat16 bf16;
typedef __bf16 bf16x8 __attribute__((ext_vector_type(8)));
typedef float f32x4 __attribute__((ext_vector_type(4)));

#define B_DIM 4
#define T_DIM 4096
#define D_DIM 1024
#define NC 64   // chunks along T
#define LC 64   // chunk length; NC*LC == T_DIM

#define M_DIM (B_DIM * T_DIM)  // 16384
#define BM 256
#define BN 256
#define BK 32
#define NT (D_DIM / BK)        // 32 K-tiles
#define GM (M_DIM / BM)        // 64
#define GN (D_DIM / BN)        // 4

// ---------------------------------------------------------------- weight cast
__global__ __launch_bounds__(256) void cast_w_kernel(
    const float* __restrict__ gw, const float* __restrict__ ow,
    bf16* __restrict__ gw16, bf16* __restrict__ ow16, int n) {
  int i = blockIdx.x * 256 + threadIdx.x;
  if (i < n) {
    gw16[i] = __float2bfloat16(gw[i]);
    ow16[i] = __float2bfloat16(ow[i]);
  }
}

// ---------------------------------------------------------------- SSM pass 1
__global__ __launch_bounds__(256) void ssm_pass1(
    const float* __restrict__ x, const float* __restrict__ A,
    const float* __restrict__ Bp, float* __restrict__ hfin) {
  const int tid  = threadIdx.x;
  const int dblk = blockIdx.x & 3;           // D/256 = 4
  const int c    = (blockIdx.x >> 2) & (NC - 1);
  const int b    = blockIdx.x >> 8;          // / (4*NC)
  const int d    = dblk * 256 + tid;
  const float a = A[d], bp = Bp[d];
  const float* p = x + ((size_t)(b * T_DIM + c * LC) * D_DIM + d);
  float h = 0.f;
#pragma unroll 4
  for (int i = 0; i < LC; ++i)
    h = fmaf(a, h, bp * p[(size_t)i * D_DIM]);
  hfin[(b * NC + c) * D_DIM + d] = h;
}

// ---------------------------------------------------------------- SSM pass 2
__global__ __launch_bounds__(256) void ssm_pass2(
    const float* __restrict__ A, const float* __restrict__ hfin,
    float* __restrict__ hin) {
  const int idx = blockIdx.x * 256 + threadIdx.x;  // B*D = 4096
  const int d = idx & (D_DIM - 1);
  const int b = idx >> 10;
  float aL = A[d];
#pragma unroll
  for (int s = 0; s < 6; ++s) aL *= aL;  // A^64 (LC = 2^6)
  float h = 0.f;
  for (int c = 0; c < NC; ++c) {
    const int o = (b * NC + c) * D_DIM + d;
    hin[o] = h;
    h = fmaf(aL, h, hfin[o]);
  }
}

// ---------------------------------------------------------------- SSM pass 3
__global__ __launch_bounds__(256) void ssm_pass3(
    const float* __restrict__ x, const float* __restrict__ A,
    const float* __restrict__ Bp, const float* __restrict__ Cp,
    const float* __restrict__ hin, bf16* __restrict__ ssm16,
    bf16* __restrict__ x16) {
  const int tid  = threadIdx.x;
  const int dblk = blockIdx.x & 3;
  const int c    = (blockIdx.x >> 2) & (NC - 1);
  const int b    = blockIdx.x >> 8;
  const int d    = dblk * 256 + tid;
  const float a = A[d], bp = Bp[d], cp = Cp[d];
  float h = hin[(b * NC + c) * D_DIM + d];
  const size_t base = (size_t)(b * T_DIM + c * LC) * D_DIM + d;
#pragma unroll 4
  for (int i = 0; i < LC; ++i) {
    const size_t o = base + (size_t)i * D_DIM;
    const float xv = x[o];
    h = fmaf(a, h, bp * xv);
    ssm16[o] = __float2bfloat16(cp * h);
    x16[o]  = __float2bfloat16(xv);
  }
}

// ---------------------------------------------------------------- GEMM 256x256
// C[m][e] = sum_k X[m][k] * W[e][k]  (+bias, +epilogue)
// R13 = R9 ring-4 schedule with the tile body split into 4 interleaved
// sub-groups (T3 per-phase interleave, m196/m248):
//   sub s: { reads a[2s..2s+1] (+ b[0..3] at s==0) ; 1 gll of STAGE(t+3) ;
//            setprio(1) 8 MFMA -> acc[2s..2s+1][*] setprio(0) }
//   tile end: vmcnt(N); s_barrier; sched_barrier(0)
// Safety audit: all buf[t] ds_reads are consumed by same-tile MFMAs before
// the tile-end barrier (lgkmcnt by compiler); STAGE(t+4)'s first gll (which
// overwrites buf[t]) is issued only after every wave crossed that barrier.
// Tile t+1's staged data (gll issued during t-2) is >=8 loads old at t's
// vmcnt(8), so the tile-end vmcnt+barrier publishes it to all waves.
// Ledger: steady vmcnt(8); tail vmcnt(4) -> vmcnt(0); last tile no barrier.
// T2 XOR swizzle both-sides (0 conflicts measured), T5 setprio, XCD chunk.
template <bool GATE>
__global__ __launch_bounds__(512) void gemm256(
    const bf16* __restrict__ Xm, const bf16* __restrict__ Wm,
    const float* __restrict__ bias, const bf16* __restrict__ ssm,
    bf16* __restrict__ Ybf, float* __restrict__ Yf) {
  // buf layout (shorts): [0,8192) = A tile 256x32, [8192,16384) = B tile 256x32
  __shared__ __align__(16) short LDS[4][16384];  // 4 x 32 KiB = 128 KiB

  const int tid  = threadIdx.x;
  const int lane = tid & 63;
  const int wave = tid >> 6;
  const int wm = wave >> 2;           // 0..1
  const int wn = wave & 3;            // 0..3
  const int l15 = lane & 15;
  // swizzled ds_read slot: true chunk (lane>>4), row parity term (l15>>1)&3
  const int sA = ((lane >> 4) ^ ((l15 >> 1) & 3)) << 3;  // shorts

  // XCD-chunked swizzle (256 blocks, 8 XCDs): 4 N-blocks per M-row share L2.
  const int bid = blockIdx.x;
  const int swz = (bid & 7) * (GM * GN / 8) + (bid >> 3);
  const int m0 = (swz >> 2) * BM;
  const int n0 = (swz & 3) * BN;

  // staging: linear LDS chunk cid -> row=cid>>2, slot=cid&3; global col-chunk
  // c = slot ^ ((row>>1)&3)  (involution matches sA on the read side).
  const int row0 = tid >> 2;
  const int c0   = (tid & 3) ^ ((row0 >> 1) & 3);
  const size_t offA0 = (size_t)(m0 + row0) * D_DIM + c0 * 8;
  const size_t offB0 = (size_t)(n0 + row0) * D_DIM + c0 * 8;

  auto gll = [](const bf16* g, short* l) {
    __builtin_amdgcn_global_load_lds(
        (const __attribute__((address_space(1))) void*)g,
        (__attribute__((address_space(3))) void*)l, 16, 0, 0);
  };
  auto STAGE_ALL = [&](int buf, int kt) {  // prologue only
    const size_t ko = (size_t)kt * BK;
    short* d0 = &LDS[buf][0] + wave * 512;
    gll(Xm + offA0 + ko,               d0);
    gll(Xm + offA0 + 128 * D_DIM + ko, d0 + 4096);
    gll(Wm + offB0 + ko,               d0 + 8192);
    gll(Wm + offB0 + 128 * D_DIM + ko, d0 + 12288);
  };

  f32x4 acc[8][4] = {};

  // prologue: prime tiles 0,1,2 (12 loads/thread in flight)
  STAGE_ALL(0, 0);
  STAGE_ALL(1, 1);
  STAGE_ALL(2, 2);
  asm volatile("s_waitcnt vmcnt(8)" ::: "memory");  // tile 0 landed (mine)
  __builtin_amdgcn_s_barrier();                     // ...and everyone's
  __builtin_amdgcn_sched_barrier(0);

#define SUBMFMA(S_)                                                         \
    __builtin_amdgcn_s_setprio(1);                                          \
    _Pragma("unroll")                                                       \
    for (int j = 0; j < 4; ++j)                                             \
      acc[2 * (S_)][j] = __builtin_amdgcn_mfma_f32_16x16x32_bf16(           \
          a[0], b[j], acc[2 * (S_)][j], 0, 0, 0);                           \
    _Pragma("unroll")                                                       \
    for (int j = 0; j < 4; ++j)                                             \
      acc[2 * (S_) + 1][j] = __builtin_amdgcn_mfma_f32_16x16x32_bf16(       \
          a[1], b[j], acc[2 * (S_) + 1][j], 0, 0, 0);                       \
    __builtin_amdgcn_s_setprio(0);

#define KTILE_BODY(T_, DO_STAGE, VMSTR, DO_BAR)                             \
  {                                                                         \
    const short* bb = &LDS[(T_) & 3][0];                                    \
    short* sd = &LDS[((T_) + 3) & 3][0] + wave * 512;                       \
    const size_t ko = (size_t)((T_) + 3) * BK;                              \
    bf16x8 a[2], b[4];                                                      \
    /* ---- sub0: b[0..3] + a[0..1], gll A-low, MFMA rows 0,1 */            \
    _Pragma("unroll")                                                       \
    for (int j = 0; j < 4; ++j)                                             \
      b[j] = *(const bf16x8*)(bb + 8192 + (wn * 64 + j * 16 + l15) * BK + sA); \
    a[0] = *(const bf16x8*)(bb + (wm * 128 + 0 * 16 + l15) * BK + sA);      \
    a[1] = *(const bf16x8*)(bb + (wm * 128 + 1 * 16 + l15) * BK + sA);      \
    if (DO_STAGE) gll(Xm + offA0 + ko, sd);                                 \
    SUBMFMA(0)                                                              \
    /* ---- sub1: a[2..3], gll A-high, MFMA rows 2,3 */                     \
    a[0] = *(const bf16x8*)(bb + (wm * 128 + 2 * 16 + l15) * BK + sA);      \
    a[1] = *(const bf16x8*)(bb + (wm * 128 + 3 * 16 + l15) * BK + sA);      \
    if (DO_STAGE) gll(Xm + offA0 + 128 * D_DIM + ko, sd + 4096);            \
    SUBMFMA(1)                                                              \
    /* ---- sub2: a[4..5], gll B-low, MFMA rows 4,5 */                      \
    a[0] = *(const bf16x8*)(bb + (wm * 128 + 4 * 16 + l15) * BK + sA);      \
    a[1] = *(const bf16x8*)(bb + (wm * 128 + 5 * 16 + l15) * BK + sA);      \
    if (DO_STAGE) gll(Wm + offB0 + ko, sd + 8192);                          \
    SUBMFMA(2)                                                              \
    /* ---- sub3: a[6..7], gll B-high, MFMA rows 6,7 */                     \
    a[0] = *(const bf16x8*)(bb + (wm * 128 + 6 * 16 + l15) * BK + sA);      \
    a[1] = *(const bf16x8*)(bb + (wm * 128 + 7 * 16 + l15) * BK + sA);      \
    if (DO_STAGE) gll(Wm + offB0 + 128 * D_DIM + ko, sd + 12288);           \
    SUBMFMA(3)                                                              \
    if (DO_BAR) {                                                           \
      asm volatile("s_waitcnt " VMSTR ::: "memory");                        \
      __builtin_amdgcn_s_barrier();                                         \
      __builtin_amdgcn_sched_barrier(0);                                    \
    }                                                                       \
  }

  for (int t = 0; t < NT - 3; ++t)        // t = 0..28: stage t+3 = 3..31
    KTILE_BODY(t, true, "vmcnt(8)", true);
  KTILE_BODY(NT - 3, false, "vmcnt(4)", true);  // tile NT-2 landed
  KTILE_BODY(NT - 2, false, "vmcnt(0)", true);  // tile NT-1 landed
  KTILE_BODY(NT - 1, false, "vmcnt(0)", false); // last tile: no barrier
#undef KTILE_BODY
#undef SUBMFMA

  // ---- epilogue: C/D layout col = lane&15, row = (lane>>4)*4 + v  [m89/m91]
#pragma unroll
  for (int i = 0; i < 8; ++i) {
#pragma unroll
    for (int j = 0; j < 4; ++j) {
      const int col = n0 + wn * 64 + j * 16 + l15;
      const float bv = bias[col];
#pragma unroll
      for (int v = 0; v < 4; ++v) {
        const int row = m0 + wm * 128 + i * 16 + (lane >> 4) * 4 + v;
        const size_t o = (size_t)row * D_DIM + col;
        const float val = acc[i][j][v] + bv;
        if (GATE) {
          const float g = 1.f / (1.f + expf(-val));
          Ybf[o] = __float2bfloat16(g * __bfloat162float(ssm[o]));
        } else {
          Yf[o] = val;
        }
      }
    }
  }
}

// ---------------------------------------------------------------- launch
extern "C" void kernel_launch(void* const* d_in, const int* in_sizes, int n_in,
                              void* d_out, int out_size, void* d_ws, size_t ws_size,
                              hipStream_t stream) {
  const float* x  = (const float*)d_in[0];
  const float* A  = (const float*)d_in[1];
  const float* Bp = (const float*)d_in[2];
  const float* Cp = (const float*)d_in[3];
  const float* gw = (const float*)d_in[4];
  const float* gb = (const float*)d_in[5];
  const float* ow = (const float*)d_in[6];
  const float* ob = (const float*)d_in[7];
  float* out = (float*)d_out;

  // workspace layout (bytes)
  const size_t NEED = 73400320;
  if (ws_size < NEED) {
    fprintf(stderr, "kernel_launch: ws_size %zu < needed %zu\n", ws_size, NEED);
    return;
  }
  char* ws = (char*)d_ws;
  bf16*  x16   = (bf16*)(ws);                   // 33,554,432 B : x cast to bf16
  bf16*  ssm16 = (bf16*)(ws + 33554432);        // 33,554,432 B : ssm, then y in-place
  bf16*  gw16  = (bf16*)(ws + 67108864);        //  2,097,152 B
  bf16*  ow16  = (bf16*)(ws + 69206016);        //  2,097,152 B
  float* hfin  = (float*)(ws + 71303168);       //  1,048,576 B
  float* hin   = (float*)(ws + 72351744);       //  1,048,576 B

  cast_w_kernel<<<(D_DIM * D_DIM) / 256, 256, 0, stream>>>(gw, ow, gw16, ow16, D_DIM * D_DIM);
  ssm_pass1<<<B_DIM * NC * (D_DIM / 256), 256, 0, stream>>>(x, A, Bp, hfin);
  ssm_pass2<<<(B_DIM * D_DIM) / 256, 256, 0, stream>>>(A, hfin, hin);
  ssm_pass3<<<B_DIM * NC * (D_DIM / 256), 256, 0, stream>>>(x, A, Bp, Cp, hin, ssm16, x16);

  // gate GEMM: y = sigmoid(x@gw^T + gb) * ssm   (written in-place over ssm16)
  gemm256<true><<<GM * GN, 512, 0, stream>>>(x16, gw16, gb, ssm16, ssm16, nullptr);
  // out GEMM: out = y@ow^T + ob  (fp32)
  gemm256<false><<<GM * GN, 512, 0, stream>>>(ssm16, ow16, ob, nullptr, nullptr, out);
}

// Round 14
// 129.230 us; speedup vs baseline: 1.3122x; 1.0317x over previous
//
#include <hip/hip_runtime.h>
#include <hip/hip_bf16.h>
#include <cstdio>

typedef __hip_bfloat16 bf16;
typedef __bf16 bf16x8 __attribute__((ext_vector_type(8)));
typedef float f32x4 __attribute__((ext_vector_type(4)));

#define B_DIM 4
#define T_DIM 4096
#define D_DIM 1024
#define NC 64   // chunks along T
#define LC 64   // chunk length; NC*LC == T_DIM

#define M_DIM (B_DIM * T_DIM)  // 16384
#define BM 256
#define BN 256
#define KSTEP 64
#define NS (D_DIM / KSTEP)     // 16 K-steps, 2 per iteration -> 8 iters
#define GM (M_DIM / BM)        // 64
#define GN (D_DIM / BN)        // 4

// ---------------------------------------------------------------- weight cast
__global__ __launch_bounds__(256) void cast_w_kernel(
    const float* __restrict__ gw, const float* __restrict__ ow,
    bf16* __restrict__ gw16, bf16* __restrict__ ow16, int n) {
  int i = blockIdx.x * 256 + threadIdx.x;
  if (i < n) {
    gw16[i] = __float2bfloat16(gw[i]);
    ow16[i] = __float2bfloat16(ow[i]);
  }
}

// ---------------------------------------------------------------- SSM pass 1
__global__ __launch_bounds__(256) void ssm_pass1(
    const float* __restrict__ x, const float* __restrict__ A,
    const float* __restrict__ Bp, float* __restrict__ hfin) {
  const int tid  = threadIdx.x;
  const int dblk = blockIdx.x & 3;           // D/256 = 4
  const int c    = (blockIdx.x >> 2) & (NC - 1);
  const int b    = blockIdx.x >> 8;          // / (4*NC)
  const int d    = dblk * 256 + tid;
  const float a = A[d], bp = Bp[d];
  const float* p = x + ((size_t)(b * T_DIM + c * LC) * D_DIM + d);
  float h = 0.f;
#pragma unroll 4
  for (int i = 0; i < LC; ++i)
    h = fmaf(a, h, bp * p[(size_t)i * D_DIM]);
  hfin[(b * NC + c) * D_DIM + d] = h;
}

// ---------------------------------------------------------------- SSM pass 2
__global__ __launch_bounds__(256) void ssm_pass2(
    const float* __restrict__ A, const float* __restrict__ hfin,
    float* __restrict__ hin) {
  const int idx = blockIdx.x * 256 + threadIdx.x;  // B*D = 4096
  const int d = idx & (D_DIM - 1);
  const int b = idx >> 10;
  float aL = A[d];
#pragma unroll
  for (int s = 0; s < 6; ++s) aL *= aL;  // A^64 (LC = 2^6)
  float h = 0.f;
  for (int c = 0; c < NC; ++c) {
    const int o = (b * NC + c) * D_DIM + d;
    hin[o] = h;
    h = fmaf(aL, h, hfin[o]);
  }
}

// ---------------------------------------------------------------- SSM pass 3
__global__ __launch_bounds__(256) void ssm_pass3(
    const float* __restrict__ x, const float* __restrict__ A,
    const float* __restrict__ Bp, const float* __restrict__ Cp,
    const float* __restrict__ hin, bf16* __restrict__ ssm16,
    bf16* __restrict__ x16) {
  const int tid  = threadIdx.x;
  const int dblk = blockIdx.x & 3;
  const int c    = (blockIdx.x >> 2) & (NC - 1);
  const int b    = blockIdx.x >> 8;
  const int d    = dblk * 256 + tid;
  const float a = A[d], bp = Bp[d], cp = Cp[d];
  float h = hin[(b * NC + c) * D_DIM + d];
  const size_t base = (size_t)(b * T_DIM + c * LC) * D_DIM + d;
#pragma unroll 4
  for (int i = 0; i < LC; ++i) {
    const size_t o = base + (size_t)i * D_DIM;
    const float xv = x[o];
    h = fmaf(a, h, bp * xv);
    ssm16[o] = __float2bfloat16(cp * h);
    x16[o]  = __float2bfloat16(xv);
  }
}

// ---------------------------------------------------------------- GEMM 256x256
// R14: faithful m201 8-phase template (plain HIP), derived from the §5
// geometry: 256x256 tile, K-step 64, 8 waves (2M x 4N), wave C = 128x64.
// LDS = 2 bufs x {A 256x64 + B 256x64} = 128 KiB. Iteration i (i=0..7)
// reads K-step 2i from buf0 (phases 1-4, one C-quadrant each = 2 frag-rows
// x 4 cols x K=64 = 16 MFMA) and K-step 2i+1 from buf1 (phases 5-8).
// Phase = { ds-reads (12 at P0: 8 b + 4 a; else 4 a) ; stage 1 half-tile
// (2 gll/thread) ; [vmcnt@ph4/8] ; barrier ; lgkmcnt(0)+sched_barrier(0)
// (rule #18) ; setprio(1) 16 MFMA setprio(0) ; barrier }.
// Staging schedule (steady, iter i, s0=2i):
//   ph1: A-lo(s0+1)->buf1  ph2: A-hi(s0+1)->buf1   [buf1-A last read ph8 i-1]
//   ph3: B-lo(s0+2)->buf0  ph4: B-hi(s0+2)->buf0   [buf0-B fully read ph1]
//   ph5: A-lo(s0+2)->buf0  ph6: A-hi(s0+2)->buf0   [buf0-A last read ph4]
//   ph7: B-lo(s0+3)->buf1  ph8: B-hi(s0+3)->buf1   [buf1-B fully read ph5]
// Safety: a gll issued in phase p follows BARRIER_B(p-1); every read of the
// region it overwrites completed before its reader's lgkmcnt(0)->MFMA->
// BARRIER_B in the region's last-read phase (listed above) -> no race.
// Ledger (2 gll/thread per half-tile): vmcnt(4)@ph4 confirms A(s0+1)+B(s0+1)
// before ph5 reads; vmcnt(4)@ph8 confirms step s0+2 before next iter ph1.
// Prologue: stage {A-lo/hi,B-lo/hi}(0)->buf0, {B-lo/hi}(1)->buf1, vmcnt(4).
// Tail (iter 7): ph1-2 stage A(15); ph4 vmcnt(0); no stages after; final
// phase drops trailing barrier.
// LDS swizzle (rule #21 both-sides): LDS chunk (row, s) holds global chunk
// (row, s ^ (row&7)); staging fetches global slot (cid&7)^((cid>>3)&7) at
// linear dest; reads use slot (kk*4+lg)^(lane&7). Banks: row stride 128 B
// = 32 banks -> XOR spreads 8 rows over 8 chunk-cols -> 2-way = free.
template <bool GATE>
__global__ __launch_bounds__(512) void gemm256(
    const bf16* __restrict__ Xm, const bf16* __restrict__ Wm,
    const float* __restrict__ bias, const bf16* __restrict__ ssm,
    bf16* __restrict__ Ybf, float* __restrict__ Yf) {
  // per buf (shorts): A-lo @0, A-hi @8192, B-lo @16384, B-hi @24576
  __shared__ __align__(16) short LDS[2][32768];  // 2 x 64 KiB

  const int tid  = threadIdx.x;
  const int lane = tid & 63;
  const int wave = tid >> 6;
  const int wm = wave >> 2;           // 0..1
  const int wn = wave & 3;            // 0..3
  const int l15 = lane & 15;
  const int lg  = lane >> 4;          // 0..3 (k-chunk group)
  const int l7  = lane & 7;

  // XCD-chunked swizzle (256 blocks, 8 XCDs): 4 N-blocks per M-row share L2.
  const int bid = blockIdx.x;
  const int swz = (bid & 7) * (GM * GN / 8) + (bid >> 3);
  const int m0 = (swz >> 2) * BM;
  const int n0 = (swz & 3) * BN;

  // staging precompute: half-tile = 128 rows x 8 chunks; cid = g*512+tid.
  const int rowOff  = tid >> 3;                              // 0..63
  const int slotOff = ((tid & 7) ^ ((tid >> 3) & 7)) * 8;    // elements

  // read precompute (swizzled chunk cols for kk=0,1)
  const int bCol0 = ((0 + lg) ^ l7) * 8;
  const int bCol1 = ((4 + lg) ^ l7) * 8;
  const int aRowBase = wm * 8192 + l15 * 64;
  const int bRowBase = 16384 + (wn >> 1) * 8192 + ((wn & 1) * 64 + l15) * 64;

  auto gll = [](const bf16* g, const short* l) {
    __builtin_amdgcn_global_load_lds(
        (const __attribute__((address_space(1))) void*)g,
        (__attribute__((address_space(3))) void*)l, 16, 0, 0);
  };
  auto STAGE1 = [&](const bf16* P, int growbase, int ldsbase, int step) {
    const size_t ko = (size_t)step * KSTEP;
#pragma unroll
    for (int g = 0; g < 2; ++g)
      gll(P + (size_t)(growbase + 64 * g + rowOff) * D_DIM + ko + slotOff,
          &LDS[0][0] + ldsbase + (g * 512 + wave * 64) * 8);
  };

  f32x4 acc[8][4] = {};
  bf16x8 bfr[2][4];

  // prologue: step 0 full -> buf0, B(1) -> buf1 (12 loads/thread)
  STAGE1(Xm, m0,       0,             0);
  STAGE1(Xm, m0 + 128, 8192,          0);
  STAGE1(Wm, n0,       16384,         0);
  STAGE1(Wm, n0 + 128, 24576,         0);
  STAGE1(Wm, n0,       32768 + 16384, 1);
  STAGE1(Wm, n0 + 128, 32768 + 24576, 1);
  asm volatile("s_waitcnt vmcnt(4)" ::: "memory");  // step-0 tiles landed
  __builtin_amdgcn_s_barrier();

#define MFMA_ __builtin_amdgcn_mfma_f32_16x16x32_bf16
#define PHASE(RB_, P_, DO_STAGE_, SPTR_, SROW_, SLDS_, SSTEP_, DO_VM_, VM_, DO_BAR_) \
  {                                                                         \
    const short* bb = &LDS[0][0] + (RB_) * 32768;                           \
    if ((P_) == 0) {                                                        \
      _Pragma("unroll")                                                     \
      for (int j = 0; j < 4; ++j) {                                         \
        bfr[0][j] = *(const bf16x8*)(bb + bRowBase + j * 1024 + bCol0);     \
        bfr[1][j] = *(const bf16x8*)(bb + bRowBase + j * 1024 + bCol1);     \
      }                                                                     \
    }                                                                       \
    bf16x8 a00 = *(const bf16x8*)(bb + aRowBase + (2*(P_)) * 1024 + bCol0); \
    bf16x8 a01 = *(const bf16x8*)(bb + aRowBase + (2*(P_)) * 1024 + bCol1); \
    bf16x8 a10 = *(const bf16x8*)(bb + aRowBase + (2*(P_)+1) * 1024 + bCol0); \
    bf16x8 a11 = *(const bf16x8*)(bb + aRowBase + (2*(P_)+1) * 1024 + bCol1); \
    if (DO_STAGE_) STAGE1(SPTR_, SROW_, SLDS_, SSTEP_);                     \
    if (DO_VM_) asm volatile("s_waitcnt " VM_ ::: "memory");                \
    __builtin_amdgcn_s_barrier();                                           \
    asm volatile("s_waitcnt lgkmcnt(0)" ::: "memory");                      \
    __builtin_amdgcn_sched_barrier(0);                                      \
    __builtin_amdgcn_s_setprio(1);                                          \
    _Pragma("unroll")                                                       \
    for (int j = 0; j < 4; ++j) {                                           \
      acc[2*(P_)][j]   = MFMA_(a00, bfr[0][j], acc[2*(P_)][j],   0, 0, 0);  \
      acc[2*(P_)][j]   = MFMA_(a01, bfr[1][j], acc[2*(P_)][j],   0, 0, 0);  \
      acc[2*(P_)+1][j] = MFMA_(a10, bfr[0][j], acc[2*(P_)+1][j], 0, 0, 0);  \
      acc[2*(P_)+1][j] = MFMA_(a11, bfr[1][j], acc[2*(P_)+1][j], 0, 0, 0);  \
    }                                                                       \
    __builtin_amdgcn_s_setprio(0);                                          \
    if (DO_BAR_) __builtin_amdgcn_s_barrier();                              \
  }

  for (int i = 0; i < 7; ++i) {
    const int s0 = 2 * i;
    PHASE(0, 0, true, Xm, m0,       32768 + 0,     s0 + 1, false, "vmcnt(0)", true)
    PHASE(0, 1, true, Xm, m0 + 128, 32768 + 8192,  s0 + 1, false, "vmcnt(0)", true)
    PHASE(0, 2, true, Wm, n0,       16384,         s0 + 2, false, "vmcnt(0)", true)
    PHASE(0, 3, true, Wm, n0 + 128, 24576,         s0 + 2, true,  "vmcnt(4)", true)
    PHASE(1, 0, true, Xm, m0,       0,             s0 + 2, false, "vmcnt(0)", true)
    PHASE(1, 1, true, Xm, m0 + 128, 8192,          s0 + 2, false, "vmcnt(0)", true)
    PHASE(1, 2, true, Wm, n0,       32768 + 16384, s0 + 3, false, "vmcnt(0)", true)
    PHASE(1, 3, true, Wm, n0 + 128, 32768 + 24576, s0 + 3, true,  "vmcnt(4)", true)
  }
  // iter 7 (steps 14,15): only A(15) still needs staging
  PHASE(0, 0, true,  Xm, m0,       32768 + 0,    15, false, "vmcnt(0)", true)
  PHASE(0, 1, true,  Xm, m0 + 128, 32768 + 8192, 15, false, "vmcnt(0)", true)
  PHASE(0, 2, false, Xm, 0, 0, 0,                    false, "vmcnt(0)", true)
  PHASE(0, 3, false, Xm, 0, 0, 0,                    true,  "vmcnt(0)", true)
  PHASE(1, 0, false, Xm, 0, 0, 0,                    false, "vmcnt(0)", true)
  PHASE(1, 1, false, Xm, 0, 0, 0,                    false, "vmcnt(0)", true)
  PHASE(1, 2, false, Xm, 0, 0, 0,                    false, "vmcnt(0)", true)
  PHASE(1, 3, false, Xm, 0, 0, 0,                    false, "vmcnt(0)", false)
#undef PHASE
#undef MFMA_

  // ---- epilogue: C/D layout col = lane&15, row = (lane>>4)*4 + v  [m89/m91]
#pragma unroll
  for (int i = 0; i < 8; ++i) {
#pragma unroll
    for (int j = 0; j < 4; ++j) {
      const int col = n0 + wn * 64 + j * 16 + l15;
      const float bv = bias[col];
#pragma unroll
      for (int v = 0; v < 4; ++v) {
        const int row = m0 + wm * 128 + i * 16 + (lane >> 4) * 4 + v;
        const size_t o = (size_t)row * D_DIM + col;
        const float val = acc[i][j][v] + bv;
        if (GATE) {
          const float g = 1.f / (1.f + expf(-val));
          Ybf[o] = __float2bfloat16(g * __bfloat162float(ssm[o]));
        } else {
          Yf[o] = val;
        }
      }
    }
  }
}

// ---------------------------------------------------------------- launch
extern "C" void kernel_launch(void* const* d_in, const int* in_sizes, int n_in,
                              void* d_out, int out_size, void* d_ws, size_t ws_size,
                              hipStream_t stream) {
  const float* x  = (const float*)d_in[0];
  const float* A  = (const float*)d_in[1];
  const float* Bp = (const float*)d_in[2];
  const float* Cp = (const float*)d_in[3];
  const float* gw = (const float*)d_in[4];
  const float* gb = (const float*)d_in[5];
  const float* ow = (const float*)d_in[6];
  const float* ob = (const float*)d_in[7];
  float* out = (float*)d_out;

  // workspace layout (bytes)
  const size_t NEED = 73400320;
  if (ws_size < NEED) {
    fprintf(stderr, "kernel_launch: ws_size %zu < needed %zu\n", ws_size, NEED);
    return;
  }
  char* ws = (char*)d_ws;
  bf16*  x16   = (bf16*)(ws);                   // 33,554,432 B : x cast to bf16
  bf16*  ssm16 = (bf16*)(ws + 33554432);        // 33,554,432 B : ssm, then y in-place
  bf16*  gw16  = (bf16*)(ws + 67108864);        //  2,097,152 B
  bf16*  ow16  = (bf16*)(ws + 69206016);        //  2,097,152 B
  float* hfin  = (float*)(ws + 71303168);       //  1,048,576 B
  float* hin   = (float*)(ws + 72351744);       //  1,048,576 B

  cast_w_kernel<<<(D_DIM * D_DIM) / 256, 256, 0, stream>>>(gw, ow, gw16, ow16, D_DIM * D_DIM);
  ssm_pass1<<<B_DIM * NC * (D_DIM / 256), 256, 0, stream>>>(x, A, Bp, hfin);
  ssm_pass2<<<(B_DIM * D_DIM) / 256, 256, 0, stream>>>(A, hfin, hin);
  ssm_pass3<<<B_DIM * NC * (D_DIM / 256), 256, 0, stream>>>(x, A, Bp, Cp, hin, ssm16, x16);

  // gate GEMM: y = sigmoid(x@gw^T + gb) * ssm   (written in-place over ssm16)
  gemm256<true><<<GM * GN, 512, 0, stream>>>(x16, gw16, gb, ssm16, ssm16, nullptr);
  // out GEMM: out = y@ow^T + ob  (fp32)
  gemm256<false><<<GM * GN, 512, 0, stream>>>(ssm16, ow16, ob, nullptr, nullptr, out);
}

// Round 15
// 127.841 us; speedup vs baseline: 1.3264x; 1.0109x over previous
//
#include <hip/hip_runtime.h>
#include <hip/hip_bf16.h>
#include <cstdio>

typedef __hip_bfloat16 bf16;
typedef __bf16 bf16x8 __attribute__((ext_vector_type(8)));
typedef float f32x4 __attribute__((ext_vector_type(4)));

#define B_DIM 4
#define T_DIM 4096
#define D_DIM 1024
#define NC 64   // chunks along T
#define LC 64   // chunk length; NC*LC == T_DIM

#define M_DIM (B_DIM * T_DIM)  // 16384
#define BM 256
#define BN 256
#define BK 32
#define NT (D_DIM / BK)        // 32 K-tiles
#define GM (M_DIM / BM)        // 64
#define GN (D_DIM / BN)        // 4

static __device__ __forceinline__ float bfbits2f(unsigned short u) {
  return __uint_as_float(((unsigned)u) << 16);
}
static __device__ __forceinline__ unsigned short f2bfbits(float f) {
  bf16 v = __float2bfloat16(f);
  return *reinterpret_cast<unsigned short*>(&v);
}

// ---------------------------------------------------------------- weight cast
__global__ __launch_bounds__(256) void cast_w_kernel(
    const float* __restrict__ gw, const float* __restrict__ ow,
    bf16* __restrict__ gw16, bf16* __restrict__ ow16, int n) {
  int i = blockIdx.x * 256 + threadIdx.x;
  if (i < n) {
    gw16[i] = __float2bfloat16(gw[i]);
    ow16[i] = __float2bfloat16(ow[i]);
  }
}

// ---------------------------------------------------------------- SSM pass 1
// Per-chunk local scan with h_in = 0 over x~ = bf16(x); emits terminal
// state hfin AND the bf16 cast x16 (fused - x is already being read).
// Thread owns channel pair (d0, d0+1): float2 in, ushort2 out.
__global__ __launch_bounds__(256) void ssm_pass1(
    const float* __restrict__ x, const float* __restrict__ A,
    const float* __restrict__ Bp, float* __restrict__ hfin,
    unsigned short* __restrict__ x16) {
  const int tid  = threadIdx.x;
  const int half = blockIdx.x & 1;            // D/512 = 2
  const int c    = (blockIdx.x >> 1) & (NC - 1);
  const int b    = blockIdx.x >> 7;           // / (2*NC)
  const int d0   = half * 512 + tid * 2;
  const float a0 = A[d0], a1 = A[d0 + 1];
  const float bp0 = Bp[d0], bp1 = Bp[d0 + 1];
  const size_t base = (size_t)(b * T_DIM + c * LC) * D_DIM + d0;
  float h0 = 0.f, h1 = 0.f;
#pragma unroll 4
  for (int i = 0; i < LC; ++i) {
    const size_t o = base + (size_t)i * D_DIM;
    const float2 xv = *reinterpret_cast<const float2*>(x + o);
    const unsigned short u0 = f2bfbits(xv.x), u1 = f2bfbits(xv.y);
    const float f0 = bfbits2f(u0), f1 = bfbits2f(u1);  // scan the ROUNDED x
    h0 = fmaf(a0, h0, bp0 * f0);
    h1 = fmaf(a1, h1, bp1 * f1);
    *reinterpret_cast<ushort2*>(x16 + o) = make_ushort2(u0, u1);
  }
  const int ho = (b * NC + c) * D_DIM + d0;
  hfin[ho] = h0;
  hfin[ho + 1] = h1;
}

// ---------------------------------------------------------------- SSM pass 2
// Serial combine over the NC chunk summaries: h_in[c] = A^LC * h_in[c-1] + hfin[c-1].
__global__ __launch_bounds__(256) void ssm_pass2(
    const float* __restrict__ A, const float* __restrict__ hfin,
    float* __restrict__ hin) {
  const int idx = blockIdx.x * 256 + threadIdx.x;  // B*D = 4096
  const int d = idx & (D_DIM - 1);
  const int b = idx >> 10;
  float aL = A[d];
#pragma unroll
  for (int s = 0; s < 6; ++s) aL *= aL;  // A^64 (LC = 2^6)
  float h = 0.f;
  for (int c = 0; c < NC; ++c) {
    const int o = (b * NC + c) * D_DIM + d;
    hin[o] = h;
    h = fmaf(aL, h, hfin[o]);
  }
}

// ---------------------------------------------------------------- SSM pass 3
// Replay local scan (seeded with h_in) from x16 - exactly reproduces
// pass1's arithmetic (both scan bf16-rounded x in fp32). Emits ssm16.
// ushort2 in, ushort2 out: 33.5 MB read + 33.5 MB write (was 134.5 MB).
__global__ __launch_bounds__(256) void ssm_pass3(
    const unsigned short* __restrict__ x16, const float* __restrict__ A,
    const float* __restrict__ Bp, const float* __restrict__ Cp,
    const float* __restrict__ hin, unsigned short* __restrict__ ssm16) {
  const int tid  = threadIdx.x;
  const int half = blockIdx.x & 1;
  const int c    = (blockIdx.x >> 1) & (NC - 1);
  const int b    = blockIdx.x >> 7;
  const int d0   = half * 512 + tid * 2;
  const float a0 = A[d0], a1 = A[d0 + 1];
  const float bp0 = Bp[d0], bp1 = Bp[d0 + 1];
  const float cp0 = Cp[d0], cp1 = Cp[d0 + 1];
  const int ho = (b * NC + c) * D_DIM + d0;
  float h0 = hin[ho], h1 = hin[ho + 1];
  const size_t base = (size_t)(b * T_DIM + c * LC) * D_DIM + d0;
#pragma unroll 4
  for (int i = 0; i < LC; ++i) {
    const size_t o = base + (size_t)i * D_DIM;
    const ushort2 u = *reinterpret_cast<const ushort2*>(x16 + o);
    h0 = fmaf(a0, h0, bp0 * bfbits2f(u.x));
    h1 = fmaf(a1, h1, bp1 * bfbits2f(u.y));
    *reinterpret_cast<ushort2*>(ssm16 + o) =
        make_ushort2(f2bfbits(cp0 * h0), f2bfbits(cp1 * h1));
  }
}

// ---------------------------------------------------------------- GEMM 256x256
// C[m][e] = sum_k X[m][k] * W[e][k]  (+bias, +epilogue)
// R15 GEMM = R9 exactly (measured best across 6 structural variants:
// 48.7 us, 710 TF). 256x256 tile, BK=32, 8 waves (2Mx4N), ring-4 LDS,
// prefetch distance 3, counted vmcnt 8/4/0 (T4), T2 XOR swizzle
// both-sides (0 conflicts measured), T5 setprio, mid-tile single barrier
// with split MFMA halves, XCD-chunked block swizzle, unpinned ds_reads
// (compiler emits fine-grained lgkmcnt).
template <bool GATE>
__global__ __launch_bounds__(512) void gemm256(
    const bf16* __restrict__ Xm, const bf16* __restrict__ Wm,
    const float* __restrict__ bias, const bf16* __restrict__ ssm,
    bf16* __restrict__ Ybf, float* __restrict__ Yf) {
  // buf layout (shorts): [0,8192) = A tile 256x32, [8192,16384) = B tile 256x32
  __shared__ __align__(16) short LDS[4][16384];  // 4 x 32 KiB = 128 KiB

  const int tid  = threadIdx.x;
  const int lane = tid & 63;
  const int wave = tid >> 6;
  const int wm = wave >> 2;           // 0..1
  const int wn = wave & 3;            // 0..3
  const int l15 = lane & 15;
  // swizzled ds_read slot: true chunk (lane>>4), row parity term (l15>>1)&3
  const int sA = ((lane >> 4) ^ ((l15 >> 1) & 3)) << 3;  // shorts

  // XCD-chunked swizzle (256 blocks, 8 XCDs): 4 N-blocks per M-row share L2.
  const int bid = blockIdx.x;
  const int swz = (bid & 7) * (GM * GN / 8) + (bid >> 3);
  const int m0 = (swz >> 2) * BM;
  const int n0 = (swz & 3) * BN;

  // staging: linear LDS chunk cid -> row=cid>>2, slot=cid&3; global col-chunk
  // c = slot ^ ((row>>1)&3)  (involution matches sA on the read side).
  const int row0 = tid >> 2;
  const int c0   = (tid & 3) ^ ((row0 >> 1) & 3);
  const size_t offA0 = (size_t)(m0 + row0) * D_DIM + c0 * 8;
  const size_t offB0 = (size_t)(n0 + row0) * D_DIM + c0 * 8;

  auto gll = [](const bf16* g, short* l) {
    __builtin_amdgcn_global_load_lds(
        (const __attribute__((address_space(1))) void*)g,
        (__attribute__((address_space(3))) void*)l, 16, 0, 0);
  };
  auto STAGE = [&](int buf, int kt) {
    const size_t ko = (size_t)kt * BK;
    short* b0 = &LDS[buf][0] + wave * 512;
    gll(Xm + offA0 + ko,               b0);
    gll(Xm + offA0 + 128 * D_DIM + ko, b0 + 4096);
    gll(Wm + offB0 + ko,               b0 + 8192);
    gll(Wm + offB0 + 128 * D_DIM + ko, b0 + 12288);
  };

  f32x4 acc[8][4] = {};

  // prologue: prime tiles 0,1,2 (12 loads/wave in flight)
  STAGE(0, 0);
  STAGE(1, 1);
  STAGE(2, 2);
  asm volatile("s_waitcnt vmcnt(8)" ::: "memory");
  __builtin_amdgcn_s_barrier();  // tile 0 staged for all waves

#define KTILE_BODY(T_, VMSTR, DO_STAGE, DO_BAR)                             \
  {                                                                         \
    const short* bb = &LDS[(T_) & 3][0];                                    \
    bf16x8 a[8], b[4];                                                      \
    /* half1 deps first: a[0..3], b[0..3]; then a[4..7] */                  \
    _Pragma("unroll")                                                       \
    for (int i = 0; i < 4; ++i)                                             \
      a[i] = *(const bf16x8*)(bb + (wm * 128 + i * 16 + l15) * BK + sA);    \
    _Pragma("unroll")                                                       \
    for (int j = 0; j < 4; ++j)                                             \
      b[j] = *(const bf16x8*)(bb + 8192 + (wn * 64 + j * 16 + l15) * BK + sA); \
    _Pragma("unroll")                                                       \
    for (int i = 4; i < 8; ++i)                                             \
      a[i] = *(const bf16x8*)(bb + (wm * 128 + i * 16 + l15) * BK + sA);    \
    if (DO_STAGE) STAGE(((T_) + 3) & 3, (T_) + 3);                          \
    __builtin_amdgcn_s_setprio(1);                                          \
    _Pragma("unroll")                                                       \
    for (int i = 0; i < 4; ++i)                                             \
      _Pragma("unroll")                                                     \
      for (int j = 0; j < 4; ++j)                                           \
        acc[i][j] =                                                         \
            __builtin_amdgcn_mfma_f32_16x16x32_bf16(a[i], b[j], acc[i][j], 0, 0, 0); \
    __builtin_amdgcn_s_setprio(0);                                          \
    if (DO_BAR) {                                                           \
      asm volatile("s_waitcnt " VMSTR ::: "memory");                        \
      __builtin_amdgcn_s_barrier();                                         \
    }                                                                       \
    __builtin_amdgcn_s_setprio(1);                                          \
    _Pragma("unroll")                                                       \
    for (int i = 4; i < 8; ++i)                                             \
      _Pragma("unroll")                                                     \
      for (int j = 0; j < 4; ++j)                                           \
        acc[i][j] =                                                         \
            __builtin_amdgcn_mfma_f32_16x16x32_bf16(a[i], b[j], acc[i][j], 0, 0, 0); \
    __builtin_amdgcn_s_setprio(0);                                          \
  }

  for (int t = 0; t < NT - 3; ++t)        // t = 0..28: stage t+3 = 3..31
    KTILE_BODY(t, "vmcnt(8)", true, true);
  KTILE_BODY(NT - 3, "vmcnt(4)", false, true);  // ensure tile NT-2 landed
  KTILE_BODY(NT - 2, "vmcnt(0)", false, true);  // ensure tile NT-1 landed
  KTILE_BODY(NT - 1, "vmcnt(0)", false, false); // last tile: no barrier
#undef KTILE_BODY

  // ---- epilogue: C/D layout col = lane&15, row = (lane>>4)*4 + v  [m89/m91]
#pragma unroll
  for (int i = 0; i < 8; ++i) {
#pragma unroll
    for (int j = 0; j < 4; ++j) {
      const int col = n0 + wn * 64 + j * 16 + l15;
      const float bv = bias[col];
#pragma unroll
      for (int v = 0; v < 4; ++v) {
        const int row = m0 + wm * 128 + i * 16 + (lane >> 4) * 4 + v;
        const size_t o = (size_t)row * D_DIM + col;
        const float val = acc[i][j][v] + bv;
        if (GATE) {
          const float g = 1.f / (1.f + expf(-val));
          Ybf[o] = __float2bfloat16(g * __bfloat162float(ssm[o]));
        } else {
          Yf[o] = val;
        }
      }
    }
  }
}

// ---------------------------------------------------------------- launch
extern "C" void kernel_launch(void* const* d_in, const int* in_sizes, int n_in,
                              void* d_out, int out_size, void* d_ws, size_t ws_size,
                              hipStream_t stream) {
  const float* x  = (const float*)d_in[0];
  const float* A  = (const float*)d_in[1];
  const float* Bp = (const float*)d_in[2];
  const float* Cp = (const float*)d_in[3];
  const float* gw = (const float*)d_in[4];
  const float* gb = (const float*)d_in[5];
  const float* ow = (const float*)d_in[6];
  const float* ob = (const float*)d_in[7];
  float* out = (float*)d_out;

  // workspace layout (bytes)
  const size_t NEED = 73400320;
  if (ws_size < NEED) {
    fprintf(stderr, "kernel_launch: ws_size %zu < needed %zu\n", ws_size, NEED);
    return;
  }
  char* ws = (char*)d_ws;
  bf16*  x16   = (bf16*)(ws);                   // 33,554,432 B : x cast to bf16
  bf16*  ssm16 = (bf16*)(ws + 33554432);        // 33,554,432 B : ssm, then y in-place
  bf16*  gw16  = (bf16*)(ws + 67108864);        //  2,097,152 B
  bf16*  ow16  = (bf16*)(ws + 69206016);        //  2,097,152 B
  float* hfin  = (float*)(ws + 71303168);       //  1,048,576 B
  float* hin   = (float*)(ws + 72351744);       //  1,048,576 B

  cast_w_kernel<<<(D_DIM * D_DIM) / 256, 256, 0, stream>>>(gw, ow, gw16, ow16, D_DIM * D_DIM);
  // pass1: 512 blocks (b, chunk, D-half), emits hfin + x16
  ssm_pass1<<<B_DIM * NC * 2, 256, 0, stream>>>(x, A, Bp, hfin,
                                                (unsigned short*)x16);
  ssm_pass2<<<(B_DIM * D_DIM) / 256, 256, 0, stream>>>(A, hfin, hin);
  // pass3: replay from x16 (bf16), emits ssm16
  ssm_pass3<<<B_DIM * NC * 2, 256, 0, stream>>>((const unsigned short*)x16, A,
                                                Bp, Cp, hin,
                                                (unsigned short*)ssm16);

  // gate GEMM: y = sigmoid(x@gw^T + gb) * ssm   (written in-place over ssm16)
  gemm256<true><<<GM * GN, 512, 0, stream>>>(x16, gw16, gb, ssm16, ssm16, nullptr);
  // out GEMM: out = y@ow^T + ob  (fp32)
  gemm256<false><<<GM * GN, 512, 0, stream>>>(ssm16, ow16, ob, nullptr, nullptr, out);
}

// Round 16
// 126.703 us; speedup vs baseline: 1.3384x; 1.0090x over previous
//
#include <hip/hip_runtime.h>
#include <hip/hip_bf16.h>
#include <cstdio>

typedef __hip_bfloat16 bf16;
typedef __bf16 bf16x8 __attribute__((ext_vector_type(8)));
typedef float f32x4 __attribute__((ext_vector_type(4)));

#define B_DIM 4
#define T_DIM 4096
#define D_DIM 1024
#define NC 64   // chunks along T
#define LC 64   // chunk length; NC*LC == T_DIM

#define M_DIM (B_DIM * T_DIM)  // 16384
#define BM 256
#define BN 256
#define BK 32
#define NT (D_DIM / BK)        // 32 K-tiles
#define GM (M_DIM / BM)        // 64
#define GN (D_DIM / BN)        // 4

static __device__ __forceinline__ float bfbits2f(unsigned short u) {
  return __uint_as_float(((unsigned)u) << 16);
}
static __device__ __forceinline__ unsigned short f2bfbits(float f) {
  bf16 v = __float2bfloat16(f);
  return *reinterpret_cast<unsigned short*>(&v);
}

// ---------------------------------------------------------------- weight cast
__global__ __launch_bounds__(256) void cast_w_kernel(
    const float* __restrict__ gw, const float* __restrict__ ow,
    bf16* __restrict__ gw16, bf16* __restrict__ ow16, int n) {
  int i = blockIdx.x * 256 + threadIdx.x;
  if (i < n) {
    gw16[i] = __float2bfloat16(gw[i]);
    ow16[i] = __float2bfloat16(ow[i]);
  }
}

// ---------------------------------------------------------------- SSM pass 1
// Per-chunk local scan with h_in = 0 over x~ = bf16(x); emits terminal
// state hfin AND the bf16 cast x16 (fused - x is already being read).
__global__ __launch_bounds__(256) void ssm_pass1(
    const float* __restrict__ x, const float* __restrict__ A,
    const float* __restrict__ Bp, float* __restrict__ hfin,
    unsigned short* __restrict__ x16) {
  const int tid  = threadIdx.x;
  const int half = blockIdx.x & 1;            // D/512 = 2
  const int c    = (blockIdx.x >> 1) & (NC - 1);
  const int b    = blockIdx.x >> 7;           // / (2*NC)
  const int d0   = half * 512 + tid * 2;
  const float a0 = A[d0], a1 = A[d0 + 1];
  const float bp0 = Bp[d0], bp1 = Bp[d0 + 1];
  const size_t base = (size_t)(b * T_DIM + c * LC) * D_DIM + d0;
  float h0 = 0.f, h1 = 0.f;
#pragma unroll 4
  for (int i = 0; i < LC; ++i) {
    const size_t o = base + (size_t)i * D_DIM;
    const float2 xv = *reinterpret_cast<const float2*>(x + o);
    const unsigned short u0 = f2bfbits(xv.x), u1 = f2bfbits(xv.y);
    const float f0 = bfbits2f(u0), f1 = bfbits2f(u1);  // scan the ROUNDED x
    h0 = fmaf(a0, h0, bp0 * f0);
    h1 = fmaf(a1, h1, bp1 * f1);
    *reinterpret_cast<ushort2*>(x16 + o) = make_ushort2(u0, u1);
  }
  const int ho = (b * NC + c) * D_DIM + d0;
  hfin[ho] = h0;
  hfin[ho + 1] = h1;
}

// ---------------------------------------------------------------- SSM pass 2
__global__ __launch_bounds__(256) void ssm_pass2(
    const float* __restrict__ A, const float* __restrict__ hfin,
    float* __restrict__ hin) {
  const int idx = blockIdx.x * 256 + threadIdx.x;  // B*D = 4096
  const int d = idx & (D_DIM - 1);
  const int b = idx >> 10;
  float aL = A[d];
#pragma unroll
  for (int s = 0; s < 6; ++s) aL *= aL;  // A^64 (LC = 2^6)
  float h = 0.f;
  for (int c = 0; c < NC; ++c) {
    const int o = (b * NC + c) * D_DIM + d;
    hin[o] = h;
    h = fmaf(aL, h, hfin[o]);
  }
}

// ---------------------------------------------------------------- GEMM 256x256
// C[m][e] = sum_k X[m][k] * W[e][k]  (+bias, +epilogue)
// GEMM core = R9 (measured best across 6 structural variants: 48.7us,
// 710 TF): 256x256 tile, BK=32, 8 waves (2Mx4N), ring-4 LDS, prefetch
// distance 3, counted vmcnt (T4), T2 XOR swizzle both-sides (0 conflicts
// measured), T5 setprio, mid-tile single barrier with split MFMA halves,
// XCD-chunked block swizzle, unpinned ds_reads.
// R16 (GATE only): ssm_pass3 FUSED into the prologue. Each block computes
// its own ssm tile [m0..m0+255][n0..n0+255] from x16 + hin (4 t-chunks x
// 256 channels = 2 (chunk,ch) pairs/thread x 64 recurrence steps), stores
// to ssm16; own epilogue re-reads it (same block/CU/XCD -> coherent; the
// pre-loop vmcnt(0)+barrier orders stores before any epilogue load).
// vmcnt ledger re-derived with prologue drained to 0: tile t's mid
// vmcnt(8) first binds at t=2 (outstanding t+1,t+2,t+3 = 12 -> waits
// t+1's 4 done); steady state identical to R9's.
template <bool GATE>
__global__ __launch_bounds__(512) void gemm256(
    const bf16* __restrict__ Xm, const bf16* __restrict__ Wm,
    const float* __restrict__ bias, const bf16* __restrict__ ssm,
    bf16* __restrict__ Ybf, float* __restrict__ Yf,
    const unsigned short* __restrict__ x16s, const float* __restrict__ Ap,
    const float* __restrict__ Bpp, const float* __restrict__ Cpp,
    const float* __restrict__ hinp) {
  // buf layout (shorts): [0,8192) = A tile 256x32, [8192,16384) = B tile 256x32
  __shared__ __align__(16) short LDS[4][16384];  // 4 x 32 KiB = 128 KiB

  const int tid  = threadIdx.x;
  const int lane = tid & 63;
  const int wave = tid >> 6;
  const int wm = wave >> 2;           // 0..1
  const int wn = wave & 3;            // 0..3
  const int l15 = lane & 15;
  // swizzled ds_read slot: true chunk (lane>>4), row parity term (l15>>1)&3
  const int sA = ((lane >> 4) ^ ((l15 >> 1) & 3)) << 3;  // shorts

  // XCD-chunked swizzle (256 blocks, 8 XCDs): 4 N-blocks per M-row share L2.
  const int bid = blockIdx.x;
  const int swz = (bid & 7) * (GM * GN / 8) + (bid >> 3);
  const int m0 = (swz >> 2) * BM;
  const int n0 = (swz & 3) * BN;

  // staging: linear LDS chunk cid -> row=cid>>2, slot=cid&3; global col-chunk
  // c = slot ^ ((row>>1)&3)  (involution matches sA on the read side).
  const int row0 = tid >> 2;
  const int c0   = (tid & 3) ^ ((row0 >> 1) & 3);
  const size_t offA0 = (size_t)(m0 + row0) * D_DIM + c0 * 8;
  const size_t offB0 = (size_t)(n0 + row0) * D_DIM + c0 * 8;

  auto gll = [](const bf16* g, short* l) {
    __builtin_amdgcn_global_load_lds(
        (const __attribute__((address_space(1))) void*)g,
        (__attribute__((address_space(3))) void*)l, 16, 0, 0);
  };
  auto STAGE = [&](int buf, int kt) {
    const size_t ko = (size_t)kt * BK;
    short* b0 = &LDS[buf][0] + wave * 512;
    gll(Xm + offA0 + ko,               b0);
    gll(Xm + offA0 + 128 * D_DIM + ko, b0 + 4096);
    gll(Wm + offB0 + ko,               b0 + 8192);
    gll(Wm + offB0 + 128 * D_DIM + ko, b0 + 12288);
  };

  f32x4 acc[8][4] = {};

  // prologue: prime tiles 0,1,2 (12 loads/wave in flight)
  STAGE(0, 0);
  STAGE(1, 1);
  STAGE(2, 2);

  if (GATE) {
    // ---- fused ssm_pass3: compute this block's ssm tile (runs while the
    // first GEMM tiles stream in). Pair p covers (chunk ck, channel ch).
    unsigned short* ssms = (unsigned short*)ssm;
    const int bb_   = m0 >> 12;            // batch index (BM=256 | 4096)
    const int cbase = (m0 & 4095) >> 6;    // first 64-step chunk
#pragma unroll
    for (int p = 0; p < 2; ++p) {
      const int idx = p * 512 + tid;
      const int ch  = idx & 255;
      const int ck  = idx >> 8;            // 0..3
      const int d   = n0 + ch;
      const float a = Ap[d], bp = Bpp[d], cp = Cpp[d];
      float h = hinp[(bb_ * NC + cbase + ck) * D_DIM + d];
      size_t o = (size_t)(m0 + ck * 64) * D_DIM + d;
#pragma unroll 8
      for (int i = 0; i < LC; ++i, o += D_DIM) {
        h = fmaf(a, h, bp * bfbits2f(x16s[o]));
        ssms[o] = f2bfbits(cp * h);
      }
    }
  }

  // drain: recurrence loads/stores + prologue gll all complete -> ledger
  // starts at 0 outstanding (see header comment).
  asm volatile("s_waitcnt vmcnt(0)" ::: "memory");
  __builtin_amdgcn_s_barrier();

#define KTILE_BODY(T_, VMSTR, DO_STAGE, DO_BAR)                             \
  {                                                                         \
    const short* bb = &LDS[(T_) & 3][0];                                    \
    bf16x8 a[8], b[4];                                                      \
    /* half1 deps first: a[0..3], b[0..3]; then a[4..7] */                  \
    _Pragma("unroll")                                                       \
    for (int i = 0; i < 4; ++i)                                             \
      a[i] = *(const bf16x8*)(bb + (wm * 128 + i * 16 + l15) * BK + sA);    \
    _Pragma("unroll")                                                       \
    for (int j = 0; j < 4; ++j)                                             \
      b[j] = *(const bf16x8*)(bb + 8192 + (wn * 64 + j * 16 + l15) * BK + sA); \
    _Pragma("unroll")                                                       \
    for (int i = 4; i < 8; ++i)                                             \
      a[i] = *(const bf16x8*)(bb + (wm * 128 + i * 16 + l15) * BK + sA);    \
    if (DO_STAGE) STAGE(((T_) + 3) & 3, (T_) + 3);                          \
    __builtin_amdgcn_s_setprio(1);                                          \
    _Pragma("unroll")                                                       \
    for (int i = 0; i < 4; ++i)                                             \
      _Pragma("unroll")                                                     \
      for (int j = 0; j < 4; ++j)                                           \
        acc[i][j] =                                                         \
            __builtin_amdgcn_mfma_f32_16x16x32_bf16(a[i], b[j], acc[i][j], 0, 0, 0); \
    __builtin_amdgcn_s_setprio(0);                                          \
    if (DO_BAR) {                                                           \
      asm volatile("s_waitcnt " VMSTR ::: "memory");                        \
      __builtin_amdgcn_s_barrier();                                         \
    }                                                                       \
    __builtin_amdgcn_s_setprio(1);                                          \
    _Pragma("unroll")                                                       \
    for (int i = 4; i < 8; ++i)                                             \
      _Pragma("unroll")                                                     \
      for (int j = 0; j < 4; ++j)                                           \
        acc[i][j] =                                                         \
            __builtin_amdgcn_mfma_f32_16x16x32_bf16(a[i], b[j], acc[i][j], 0, 0, 0); \
    __builtin_amdgcn_s_setprio(0);                                          \
  }

  for (int t = 0; t < NT - 3; ++t)        // t = 0..28: stage t+3 = 3..31
    KTILE_BODY(t, "vmcnt(8)", true, true);
  KTILE_BODY(NT - 3, "vmcnt(4)", false, true);  // ensure tile NT-2 landed
  KTILE_BODY(NT - 2, "vmcnt(0)", false, true);  // ensure tile NT-1 landed
  KTILE_BODY(NT - 1, "vmcnt(0)", false, false); // last tile: no barrier
#undef KTILE_BODY

  // ---- epilogue: C/D layout col = lane&15, row = (lane>>4)*4 + v  [m89/m91]
#pragma unroll
  for (int i = 0; i < 8; ++i) {
#pragma unroll
    for (int j = 0; j < 4; ++j) {
      const int col = n0 + wn * 64 + j * 16 + l15;
      const float bv = bias[col];
#pragma unroll
      for (int v = 0; v < 4; ++v) {
        const int row = m0 + wm * 128 + i * 16 + (lane >> 4) * 4 + v;
        const size_t o = (size_t)row * D_DIM + col;
        const float val = acc[i][j][v] + bv;
        if (GATE) {
          const float g = 1.f / (1.f + expf(-val));
          Ybf[o] = __float2bfloat16(g * __bfloat162float(ssm[o]));
        } else {
          Yf[o] = val;
        }
      }
    }
  }
}

// ---------------------------------------------------------------- launch
extern "C" void kernel_launch(void* const* d_in, const int* in_sizes, int n_in,
                              void* d_out, int out_size, void* d_ws, size_t ws_size,
                              hipStream_t stream) {
  const float* x  = (const float*)d_in[0];
  const float* A  = (const float*)d_in[1];
  const float* Bp = (const float*)d_in[2];
  const float* Cp = (const float*)d_in[3];
  const float* gw = (const float*)d_in[4];
  const float* gb = (const float*)d_in[5];
  const float* ow = (const float*)d_in[6];
  const float* ob = (const float*)d_in[7];
  float* out = (float*)d_out;

  // workspace layout (bytes)
  const size_t NEED = 73400320;
  if (ws_size < NEED) {
    fprintf(stderr, "kernel_launch: ws_size %zu < needed %zu\n", ws_size, NEED);
    return;
  }
  char* ws = (char*)d_ws;
  bf16*  x16   = (bf16*)(ws);                   // 33,554,432 B : x cast to bf16
  bf16*  ssm16 = (bf16*)(ws + 33554432);        // 33,554,432 B : ssm, then y in-place
  bf16*  gw16  = (bf16*)(ws + 67108864);        //  2,097,152 B
  bf16*  ow16  = (bf16*)(ws + 69206016);        //  2,097,152 B
  float* hfin  = (float*)(ws + 71303168);       //  1,048,576 B
  float* hin   = (float*)(ws + 72351744);       //  1,048,576 B

  cast_w_kernel<<<(D_DIM * D_DIM) / 256, 256, 0, stream>>>(gw, ow, gw16, ow16, D_DIM * D_DIM);
  // pass1: 512 blocks (b, chunk, D-half), emits hfin + x16
  ssm_pass1<<<B_DIM * NC * 2, 256, 0, stream>>>(x, A, Bp, hfin,
                                                (unsigned short*)x16);
  ssm_pass2<<<(B_DIM * D_DIM) / 256, 256, 0, stream>>>(A, hfin, hin);

  // gate GEMM with fused ssm_pass3: computes ssm16 tile-locally, then
  // y = sigmoid(x@gw^T + gb) * ssm  (written in-place over ssm16)
  gemm256<true><<<GM * GN, 512, 0, stream>>>(
      x16, gw16, gb, ssm16, ssm16, nullptr,
      (const unsigned short*)x16, A, Bp, Cp, hin);
  // out GEMM: out = y@ow^T + ob  (fp32)
  gemm256<false><<<GM * GN, 512, 0, stream>>>(
      ssm16, ow16, ob, nullptr, nullptr, out,
      nullptr, nullptr, nullptr, nullptr, nullptr);
}

// Round 17
// 125.432 us; speedup vs baseline: 1.3519x; 1.0101x over previous
//
#include <hip/hip_runtime.h>
#include <hip/hip_bf16.h>
#include <cstdio>

typedef __hip_bfloat16 bf16;
typedef __bf16 bf16x8 __attribute__((ext_vector_type(8)));
typedef float f32x4 __attribute__((ext_vector_type(4)));

#define B_DIM 4
#define T_DIM 4096
#define D_DIM 1024
#define NC 64   // chunks along T
#define LC 64   // chunk length; NC*LC == T_DIM

#define M_DIM (B_DIM * T_DIM)  // 16384
#define BM 256
#define BN 256
#define BK 32
#define NT (D_DIM / BK)        // 32 K-tiles
#define GM (M_DIM / BM)        // 64
#define GN (D_DIM / BN)        // 4

static __device__ __forceinline__ float bfbits2f(unsigned short u) {
  return __uint_as_float(((unsigned)u) << 16);
}
static __device__ __forceinline__ unsigned short f2bfbits(float f) {
  bf16 v = __float2bfloat16(f);
  return *reinterpret_cast<unsigned short*>(&v);
}

// ---------------------------------------------------------------- weight cast
__global__ __launch_bounds__(256) void cast_w_kernel(
    const float* __restrict__ gw, const float* __restrict__ ow,
    bf16* __restrict__ gw16, bf16* __restrict__ ow16, int n) {
  int i = blockIdx.x * 256 + threadIdx.x;
  if (i < n) {
    gw16[i] = __float2bfloat16(gw[i]);
    ow16[i] = __float2bfloat16(ow[i]);
  }
}

// ---------------------------------------------------------------- SSM pass 1
__global__ __launch_bounds__(256) void ssm_pass1(
    const float* __restrict__ x, const float* __restrict__ A,
    const float* __restrict__ Bp, float* __restrict__ hfin,
    unsigned short* __restrict__ x16) {
  const int tid  = threadIdx.x;
  const int half = blockIdx.x & 1;            // D/512 = 2
  const int c    = (blockIdx.x >> 1) & (NC - 1);
  const int b    = blockIdx.x >> 7;           // / (2*NC)
  const int d0   = half * 512 + tid * 2;
  const float a0 = A[d0], a1 = A[d0 + 1];
  const float bp0 = Bp[d0], bp1 = Bp[d0 + 1];
  const size_t base = (size_t)(b * T_DIM + c * LC) * D_DIM + d0;
  float h0 = 0.f, h1 = 0.f;
#pragma unroll 4
  for (int i = 0; i < LC; ++i) {
    const size_t o = base + (size_t)i * D_DIM;
    const float2 xv = *reinterpret_cast<const float2*>(x + o);
    const unsigned short u0 = f2bfbits(xv.x), u1 = f2bfbits(xv.y);
    const float f0 = bfbits2f(u0), f1 = bfbits2f(u1);  // scan the ROUNDED x
    h0 = fmaf(a0, h0, bp0 * f0);
    h1 = fmaf(a1, h1, bp1 * f1);
    *reinterpret_cast<ushort2*>(x16 + o) = make_ushort2(u0, u1);
  }
  const int ho = (b * NC + c) * D_DIM + d0;
  hfin[ho] = h0;
  hfin[ho + 1] = h1;
}

// ---------------------------------------------------------------- SSM pass 2
__global__ __launch_bounds__(256) void ssm_pass2(
    const float* __restrict__ A, const float* __restrict__ hfin,
    float* __restrict__ hin) {
  const int idx = blockIdx.x * 256 + threadIdx.x;  // B*D = 4096
  const int d = idx & (D_DIM - 1);
  const int b = idx >> 10;
  float aL = A[d];
#pragma unroll
  for (int s = 0; s < 6; ++s) aL *= aL;  // A^64 (LC = 2^6)
  float h = 0.f;
  for (int c = 0; c < NC; ++c) {
    const int o = (b * NC + c) * D_DIM + d;
    hin[o] = h;
    h = fmaf(aL, h, hfin[o]);
  }
}

// ---------------------------------------------------------------- GEMM 256x256
// GEMM core = R9 (best of 6 variants: 48.7us/710TF). R17: the fused ssm
// recurrence (R16) is PIPELINED through the K-loop instead of serialized:
//  - 16 chunks x 4 steps x 2 chains; chunk t's 8 loads issue at tile t
//    (into reg set rlA/rlB by parity), chain FMAs + 8 stores run at tile
//    t+2 (same parity set; WAR safe by in-order issue). 2-tile distance
//    keeps the compiler's load-use wait loose (~vmcnt(24)) so it never
//    drains the staging pipeline.
//  - vmcnt ledger counts ALL vm ops younger than the staging target
//    (vmcnt retires in issue order). Per-tile ops: S(t+3):4, stores:8,
//    loads:8. Younger-of-S(t+1) at tile t: t0:16 t1:24 t2:40 t3:48
//    t4-15:56 t16:48 t17:40 t18:24 t19:16 t20-28:8 t29:4 t30/31:0.
//  - rec stores drained by t30's vmcnt(0)+barrier before epilogue reads
//    ssm (visibility proven by R16 passing).
//  - both chains share channel d (ck, ck+2) -> one param set; second
//    chain offsets are literal +128*D_DIM.
// T2 XOR swizzle both-sides (0 conflicts), T5 setprio, mid-tile barrier
// with split MFMA halves, XCD-chunked swizzle, unpinned ds_reads.
template <bool GATE>
__global__ __launch_bounds__(512) void gemm256(
    const bf16* __restrict__ Xm, const bf16* __restrict__ Wm,
    const float* __restrict__ bias, const bf16* __restrict__ ssm,
    bf16* __restrict__ Ybf, float* __restrict__ Yf,
    const unsigned short* __restrict__ x16s, const float* __restrict__ Ap,
    const float* __restrict__ Bpp, const float* __restrict__ Cpp,
    const float* __restrict__ hinp) {
  __shared__ __align__(16) short LDS[4][16384];  // 4 x 32 KiB = 128 KiB

  const int tid  = threadIdx.x;
  const int lane = tid & 63;
  const int wave = tid >> 6;
  const int wm = wave >> 2;           // 0..1
  const int wn = wave & 3;            // 0..3
  const int l15 = lane & 15;
  const int sA = ((lane >> 4) ^ ((l15 >> 1) & 3)) << 3;  // shorts

  const int bid = blockIdx.x;
  const int swz = (bid & 7) * (GM * GN / 8) + (bid >> 3);
  const int m0 = (swz >> 2) * BM;
  const int n0 = (swz & 3) * BN;

  const int row0 = tid >> 2;
  const int c0   = (tid & 3) ^ ((row0 >> 1) & 3);
  const size_t offA0 = (size_t)(m0 + row0) * D_DIM + c0 * 8;
  const size_t offB0 = (size_t)(n0 + row0) * D_DIM + c0 * 8;

  auto gll = [](const bf16* g, short* l) {
    __builtin_amdgcn_global_load_lds(
        (const __attribute__((address_space(1))) void*)g,
        (__attribute__((address_space(3))) void*)l, 16, 0, 0);
  };
  auto STAGE = [&](int buf, int kt) {
    const size_t ko = (size_t)kt * BK;
    short* b0 = &LDS[buf][0] + wave * 512;
    gll(Xm + offA0 + ko,               b0);
    gll(Xm + offA0 + 128 * D_DIM + ko, b0 + 4096);
    gll(Wm + offB0 + ko,               b0 + 8192);
    gll(Wm + offB0 + 128 * D_DIM + ko, b0 + 12288);
  };

  f32x4 acc[8][4] = {};

  // ---- rec chain state (GATE only; DCE'd otherwise).
  // chain0: (ck=tid>>8, ch=tid&255); chain1: ck+2, same ch -> same params.
  float ar = 0.f, bpr = 0.f, cpr = 0.f, h0 = 0.f, h1 = 0.f;
  size_t lo0 = 0, so0 = 0;
  unsigned short* ssms = (unsigned short*)ssm;
  unsigned short rlA[8], rlB[8];
  if (GATE) {
    const int ch = tid & 255;
    const int ck = tid >> 8;             // 0..1
    const int d  = n0 + ch;
    ar = Ap[d]; bpr = Bpp[d]; cpr = Cpp[d];
    const int bb_   = m0 >> 12;
    const int cbase = (m0 & 4095) >> 6;
    h0 = hinp[(bb_ * NC + cbase + ck) * D_DIM + d];
    h1 = hinp[(bb_ * NC + cbase + ck + 2) * D_DIM + d];
    lo0 = (size_t)(m0 + ck * 64) * D_DIM + d;
    so0 = lo0;
  }

  // prologue: prime tiles 0,1,2 (rec param loads are OLDER than S0).
  STAGE(0, 0);
  STAGE(1, 1);
  STAGE(2, 2);
  asm volatile("s_waitcnt vmcnt(8)" ::: "memory");
  __builtin_amdgcn_s_barrier();  // tile 0 staged for all waves

  // MODE_: 0 none, 1 load-only, 2 comp+load, 3 comp-only
#define RECBLK(RL_, MODE_)                                                  \
    if (GATE && (MODE_) >= 2) {                                             \
      _Pragma("unroll")                                                     \
      for (int s = 0; s < 4; ++s) {                                         \
        h0 = fmaf(ar, h0, bpr * bfbits2f(RL_[2 * s]));                      \
        ssms[so0 + (size_t)s * D_DIM] = f2bfbits(cpr * h0);                 \
        h1 = fmaf(ar, h1, bpr * bfbits2f(RL_[2 * s + 1]));                  \
        ssms[so0 + (size_t)(128 + s) * D_DIM] = f2bfbits(cpr * h1);         \
      }                                                                     \
      so0 += 4 * D_DIM;                                                     \
    }                                                                       \
    if (GATE && ((MODE_) == 1 || (MODE_) == 2)) {                           \
      _Pragma("unroll")                                                     \
      for (int s = 0; s < 4; ++s) {                                         \
        RL_[2 * s]     = x16s[lo0 + (size_t)s * D_DIM];                     \
        RL_[2 * s + 1] = x16s[lo0 + (size_t)(128 + s) * D_DIM];             \
      }                                                                     \
      lo0 += 4 * D_DIM;                                                     \
    }

#define KTILE_BODY(T_, VMSTR, DO_STAGE, DO_BAR, RL_, MODE_)                 \
  {                                                                         \
    const short* bb = &LDS[(T_) & 3][0];                                    \
    bf16x8 a[8], b[4];                                                      \
    _Pragma("unroll")                                                       \
    for (int i = 0; i < 4; ++i)                                             \
      a[i] = *(const bf16x8*)(bb + (wm * 128 + i * 16 + l15) * BK + sA);    \
    _Pragma("unroll")                                                       \
    for (int j = 0; j < 4; ++j)                                             \
      b[j] = *(const bf16x8*)(bb + 8192 + (wn * 64 + j * 16 + l15) * BK + sA); \
    _Pragma("unroll")                                                       \
    for (int i = 4; i < 8; ++i)                                             \
      a[i] = *(const bf16x8*)(bb + (wm * 128 + i * 16 + l15) * BK + sA);    \
    if (DO_STAGE) STAGE(((T_) + 3) & 3, (T_) + 3);                          \
    RECBLK(RL_, MODE_)                                                      \
    __builtin_amdgcn_s_setprio(1);                                          \
    _Pragma("unroll")                                                       \
    for (int i = 0; i < 4; ++i)                                             \
      _Pragma("unroll")                                                     \
      for (int j = 0; j < 4; ++j)                                           \
        acc[i][j] =                                                         \
            __builtin_amdgcn_mfma_f32_16x16x32_bf16(a[i], b[j], acc[i][j], 0, 0, 0); \
    __builtin_amdgcn_s_setprio(0);                                          \
    if (DO_BAR) {                                                           \
      asm volatile("s_waitcnt " VMSTR ::: "memory");                        \
      __builtin_amdgcn_s_barrier();                                         \
    }                                                                       \
    __builtin_amdgcn_s_setprio(1);                                          \
    _Pragma("unroll")                                                       \
    for (int i = 4; i < 8; ++i)                                             \
      _Pragma("unroll")                                                     \
      for (int j = 0; j < 4; ++j)                                           \
        acc[i][j] =                                                         \
            __builtin_amdgcn_mfma_f32_16x16x32_bf16(a[i], b[j], acc[i][j], 0, 0, 0); \
    __builtin_amdgcn_s_setprio(0);                                          \
  }

  if (GATE) {
    KTILE_BODY(0, "vmcnt(16)", true, true, rlA, 1)
    KTILE_BODY(1, "vmcnt(24)", true, true, rlB, 1)
    KTILE_BODY(2, "vmcnt(40)", true, true, rlA, 2)
    KTILE_BODY(3, "vmcnt(48)", true, true, rlB, 2)
    for (int t = 4; t <= 14; t += 2) {   // pairs (4,5)...(14,15)
      KTILE_BODY(t,     "vmcnt(56)", true, true, rlA, 2)
      KTILE_BODY(t + 1, "vmcnt(56)", true, true, rlB, 2)
    }
    KTILE_BODY(16, "vmcnt(48)", true, true, rlA, 3)
    KTILE_BODY(17, "vmcnt(40)", true, true, rlB, 3)
    KTILE_BODY(18, "vmcnt(24)", true, true, rlA, 0)
    KTILE_BODY(19, "vmcnt(16)", true, true, rlA, 0)
    for (int t = 20; t < NT - 3; ++t)
      KTILE_BODY(t, "vmcnt(8)", true, true, rlA, 0)
  } else {
    for (int t = 0; t < NT - 3; ++t)
      KTILE_BODY(t, "vmcnt(8)", true, true, rlA, 0)
  }
  KTILE_BODY(NT - 3, "vmcnt(4)", false, true, rlA, 0)
  KTILE_BODY(NT - 2, "vmcnt(0)", false, true, rlA, 0)   // drains rec stores
  KTILE_BODY(NT - 1, "vmcnt(0)", false, false, rlA, 0)
#undef KTILE_BODY
#undef RECBLK

  // ---- epilogue: C/D layout col = lane&15, row = (lane>>4)*4 + v  [m89/m91]
#pragma unroll
  for (int i = 0; i < 8; ++i) {
#pragma unroll
    for (int j = 0; j < 4; ++j) {
      const int col = n0 + wn * 64 + j * 16 + l15;
      const float bv = bias[col];
#pragma unroll
      for (int v = 0; v < 4; ++v) {
        const int row = m0 + wm * 128 + i * 16 + (lane >> 4) * 4 + v;
        const size_t o = (size_t)row * D_DIM + col;
        const float val = acc[i][j][v] + bv;
        if (GATE) {
          const float g = 1.f / (1.f + expf(-val));
          Ybf[o] = __float2bfloat16(g * __bfloat162float(ssm[o]));
        } else {
          Yf[o] = val;
        }
      }
    }
  }
}

// ---------------------------------------------------------------- launch
extern "C" void kernel_launch(void* const* d_in, const int* in_sizes, int n_in,
                              void* d_out, int out_size, void* d_ws, size_t ws_size,
                              hipStream_t stream) {
  const float* x  = (const float*)d_in[0];
  const float* A  = (const float*)d_in[1];
  const float* Bp = (const float*)d_in[2];
  const float* Cp = (const float*)d_in[3];
  const float* gw = (const float*)d_in[4];
  const float* gb = (const float*)d_in[5];
  const float* ow = (const float*)d_in[6];
  const float* ob = (const float*)d_in[7];
  float* out = (float*)d_out;

  // workspace layout (bytes)
  const size_t NEED = 73400320;
  if (ws_size < NEED) {
    fprintf(stderr, "kernel_launch: ws_size %zu < needed %zu\n", ws_size, NEED);
    return;
  }
  char* ws = (char*)d_ws;
  bf16*  x16   = (bf16*)(ws);                   // 33,554,432 B : x cast to bf16
  bf16*  ssm16 = (bf16*)(ws + 33554432);        // 33,554,432 B : ssm, then y in-place
  bf16*  gw16  = (bf16*)(ws + 67108864);        //  2,097,152 B
  bf16*  ow16  = (bf16*)(ws + 69206016);        //  2,097,152 B
  float* hfin  = (float*)(ws + 71303168);       //  1,048,576 B
  float* hin   = (float*)(ws + 72351744);       //  1,048,576 B

  cast_w_kernel<<<(D_DIM * D_DIM) / 256, 256, 0, stream>>>(gw, ow, gw16, ow16, D_DIM * D_DIM);
  ssm_pass1<<<B_DIM * NC * 2, 256, 0, stream>>>(x, A, Bp, hfin,
                                                (unsigned short*)x16);
  ssm_pass2<<<(B_DIM * D_DIM) / 256, 256, 0, stream>>>(A, hfin, hin);

  // gate GEMM with PIPELINED fused ssm recurrence, then
  // y = sigmoid(x@gw^T + gb) * ssm  (written in-place over ssm16)
  gemm256<true><<<GM * GN, 512, 0, stream>>>(
      x16, gw16, gb, ssm16, ssm16, nullptr,
      (const unsigned short*)x16, A, Bp, Cp, hin);
  // out GEMM: out = y@ow^T + ob  (fp32)
  gemm256<false><<<GM * GN, 512, 0, stream>>>(
      ssm16, ow16, ob, nullptr, nullptr, out,
      nullptr, nullptr, nullptr, nullptr, nullptr);
}